// Round 18
// baseline (5070.893 us; speedup 1.0000x reference)
//
#include <hip/hip_runtime.h>
#include <hip/hip_bf16.h>

#define LL 1568
#define EE 384
#define DD 768
#define BB 4

typedef float f32x4 __attribute__((ext_vector_type(4)));
typedef float f32x2 __attribute__((ext_vector_type(2)));
typedef unsigned short u16x2 __attribute__((ext_vector_type(2)));
typedef unsigned short u16x4 __attribute__((ext_vector_type(4)));
typedef unsigned short u16x8 __attribute__((ext_vector_type(8)));
typedef __bf16 bf16x8 __attribute__((ext_vector_type(8)));

__device__ inline unsigned short f2bf(float f) {
    unsigned int u = __builtin_bit_cast(unsigned int, f);
    u += 0x7fffu + ((u >> 16) & 1u);
    return (unsigned short)(u >> 16);
}
__device__ inline float bf2f(unsigned short u) {
    unsigned int v = ((unsigned int)u) << 16;
    return __builtin_bit_cast(float, v);
}
__device__ inline float silu_f(float v) { return v / (1.f + __expf(-v)); }
__device__ inline float exp2_f(float v) { return __builtin_amdgcn_exp2f(v); }

// ---------------- weight fp32 -> bf16 ----------------
__global__ __launch_bounds__(256) void k_cvt(const float* __restrict__ src,
                                             unsigned short* __restrict__ dst, int n4) {
    int i = blockIdx.x * 256 + threadIdx.x;
    int stride = gridDim.x * 256;
    for (; i < n4; i += stride) {
        f32x4 v = *(const f32x4*)(src + (size_t)i * 4);
        u16x4 o;
#pragma unroll
        for (int j = 0; j < 4; j++) o[j] = f2bf(v[j]);
        *(u16x4*)(dst + (size_t)i * 4) = o;
    }
}

// xpw [24][56][768] f32 -> [24][64][768] bf16 (rows 56..63 zero)
__global__ __launch_bounds__(256) void k_pad_xpw(const float* __restrict__ src,
                                                 unsigned short* __restrict__ dst) {
    const int total = 24 * 64 * 768;
    for (int i = blockIdx.x * 256 + threadIdx.x; i < total; i += gridDim.x * 256) {
        int l = i / (64 * 768);
        int r = (i / 768) % 64;
        int dcol = i % 768;
        dst[i] = (r < 56) ? f2bf(src[((size_t)l * 56 + r) * 768 + dcol]) : (unsigned short)0;
    }
}

// dtw [24][768][24] f32 -> [24][768][32] bf16 (cols 24..31 zero)
__global__ __launch_bounds__(256) void k_pad_dtw(const float* __restrict__ src,
                                                 unsigned short* __restrict__ dst) {
    const int total = 24 * 768 * 32;
    for (int i = blockIdx.x * 256 + threadIdx.x; i < total; i += gridDim.x * 256) {
        int kk = i & 31;
        int nrow = i >> 5;
        dst[i] = (kk < 24) ? f2bf(src[(size_t)nrow * 24 + kk]) : (unsigned short)0;
    }
}

// ---------------- patch extraction (bf16 out) ----------------
__global__ __launch_bounds__(256) void k_patch(const float* __restrict__ x,
                                               unsigned short* __restrict__ patches) {
    int bid = blockIdx.x;
    int b = bid / LL, rr = bid % LL, t = rr / 196, pp = rr % 196, hp = pp / 14, wp = pp % 14;
    for (int k = threadIdx.x; k < 768; k += 256) {
        int c = k >> 8, rem = k & 255, i = rem >> 4, j = rem & 15;
        patches[(size_t)bid * 768 + k] =
            f2bf(x[(((size_t)(b * 3 + c) * 8 + t) * 224 + hp * 16 + i) * 224 + wp * 16 + j]);
    }
}

// ---------------- GEMM: C[m][n] = sum_k A[m][k] * W[n][k]  (bf16 in, MFMA) ----------------
// EPI: 0 none, 1 patch-add (bf16 Cb), 2 bias+relu (f32), 3 bias+softplus (bf16, dual-dir W)
template <int EPI, bool ASUM, bool OUTBF, int NTILE = 128>
__global__ __launch_bounds__(256) void k_gemm(
    const unsigned short* __restrict__ A, const unsigned short* __restrict__ A2,
    const unsigned short* __restrict__ W, const unsigned short* __restrict__ W2,
    float* __restrict__ C, unsigned short* __restrict__ Cb, int K, int ldc,
    const float* __restrict__ bias, const float* __restrict__ bias2,
    const float* __restrict__ pos, const float* __restrict__ tpos) {
    const int tid = threadIdx.x;
    const int m0 = blockIdx.y * 128;
    const int n0 = blockIdx.x * NTILE;
    constexpr int NFRAG = NTILE / 32;
    constexpr int WLOAD = NTILE / 64;
    __shared__ unsigned short As[128 * 40];
    __shared__ unsigned short Ws[NTILE * 40];
    const int sr = tid >> 2;
    const int skc = tid & 3;

    const unsigned short* Wp = W;
    const float* biasp = bias;
    if constexpr (EPI == 3) {
        if (m0 >= 6272) { Wp = W2; biasp = bias2; }
    }

    f32x4 acc[4][NFRAG];
#pragma unroll
    for (int mi = 0; mi < 4; mi++)
#pragma unroll
        for (int ni = 0; ni < NFRAG; ni++) acc[mi][ni] = (f32x4){0.f, 0.f, 0.f, 0.f};

    const int lane = tid & 63;
    const int wv = tid >> 6;
    const int wm = (wv & 1) << 6;
    const int wn = (wv >> 1) * (NTILE / 2);
    const int lr = lane & 15;
    const int kg = lane >> 4;

    u16x8 ar[2], wr_[WLOAD];
    auto loadT = [&](int kt) {
#pragma unroll
        for (int i = 0; i < 2; i++) {
            size_t ka = (size_t)(m0 + sr + 64 * i) * K + kt * 32 + skc * 8;
            u16x8 v = *(const u16x8*)(A + ka);
            if constexpr (ASUM) {
                u16x8 v2 = *(const u16x8*)(A2 + ka);
#pragma unroll
                for (int j = 0; j < 8; j++) v[j] = f2bf(bf2f(v[j]) + bf2f(v2[j]));
            }
            ar[i] = v;
        }
#pragma unroll
        for (int i = 0; i < WLOAD; i++)
            wr_[i] = *(const u16x8*)(Wp + (size_t)(n0 + sr + 64 * i) * K + kt * 32 + skc * 8);
    };

    const int nK = K >> 5;
    loadT(0);
    for (int kt = 0; kt < nK; ++kt) {
#pragma unroll
        for (int i = 0; i < 2; i++)
            *(u16x8*)&As[(sr + 64 * i) * 40 + skc * 8] = ar[i];
#pragma unroll
        for (int i = 0; i < WLOAD; i++)
            *(u16x8*)&Ws[(sr + 64 * i) * 40 + skc * 8] = wr_[i];
        __syncthreads();
        if (kt + 1 < nK) loadT(kt + 1);
        bf16x8 af[4], bfm[NFRAG];
#pragma unroll
        for (int mi = 0; mi < 4; mi++)
            af[mi] = *(const bf16x8*)&As[(wm + mi * 16 + lr) * 40 + kg * 8];
#pragma unroll
        for (int ni = 0; ni < NFRAG; ni++)
            bfm[ni] = *(const bf16x8*)&Ws[(wn + ni * 16 + lr) * 40 + kg * 8];
#pragma unroll
        for (int mi = 0; mi < 4; mi++)
#pragma unroll
            for (int ni = 0; ni < NFRAG; ni++)
                acc[mi][ni] = __builtin_amdgcn_mfma_f32_16x16x32_bf16(af[mi], bfm[ni], acc[mi][ni], 0, 0, 0);
        __syncthreads();
    }

#pragma unroll
    for (int mi = 0; mi < 4; mi++)
#pragma unroll
        for (int ni = 0; ni < NFRAG; ni++)
#pragma unroll
            for (int j = 0; j < 4; j++) {
                int m = m0 + wm + mi * 16 + kg * 4 + j;
                int n = n0 + wn + ni * 16 + lr;
                float v = acc[mi][ni][j];
                if constexpr (EPI == 1) {
                    int rr = m % LL;
                    int t = rr / 196, p = rr % 196;
                    v += bias[n] + pos[p * EE + n] + tpos[t * EE + n];
                    Cb[(size_t)m * ldc + n] = f2bf(v);
                } else if constexpr (EPI == 2) {
                    v += bias[n];
                    v = fmaxf(v, 0.f);
                    C[(size_t)m * ldc + n] = v;
                } else if constexpr (EPI == 3) {
                    v += biasp[n];
                    float sp = (v > 20.f) ? v : log1pf(__expf(v));
                    Cb[(size_t)m * ldc + n] = f2bf(sp);
                } else {
                    if constexpr (OUTBF)
                        Cb[(size_t)m * ldc + n] = f2bf(v);
                    else
                        C[(size_t)m * ldc + n] = v;
                }
            }
}

// ---------------- importance logits + sigmoid scale (bf16 hidden in-place) ----------------
__global__ __launch_bounds__(64) void k_logits(const float* __restrict__ h1, const float* __restrict__ w2,
                                               const float* __restrict__ b2,
                                               unsigned short* __restrict__ xseq,
                                               float* __restrict__ logits_out) {
    int row = blockIdx.x;
    int lane = threadIdx.x;
    float acc = 0.f;
#pragma unroll
    for (int i = 0; i < 6; i++) {
        int e = lane + i * 64;
        acc += h1[(size_t)row * EE + e] * w2[e];
    }
#pragma unroll
    for (int off = 32; off >= 1; off >>= 1) acc += __shfl_xor(acc, off);
    float logit = acc + b2[0];
    if (lane == 0) logits_out[row] = logit;
    float sg = 1.f / (1.f + __expf(-logit));
#pragma unroll
    for (int i = 0; i < 6; i++) {
        int e = lane + i * 64;
        size_t idx = (size_t)row * EE + e;
        xseq[idx] = f2bf(bf2f(xseq[idx]) * sg);
    }
}

// ---------------- residual add + rmsnorm (bf16 hidden, f32 resid) ----------------
template <bool OBF>
__global__ __launch_bounds__(256) void k_norm(const unsigned short* __restrict__ hidden,
                                              float* __restrict__ resid,
                                              const float* __restrict__ wn, float* __restrict__ outf,
                                              unsigned short* __restrict__ outb,
                                              int first, int writeResid) {
    int row = blockIdx.x * 4 + (threadIdx.x >> 6);
    int lane = threadIdx.x & 63;
    size_t base = (size_t)row * EE;
    float v[6];
    float ss = 0.f;
#pragma unroll
    for (int i = 0; i < 6; i++) {
        int e = lane + i * 64;
        float h = bf2f(hidden[base + e]);
        float r = first ? 0.f : resid[base + e];
        float s = h + r;
        v[i] = s;
        ss += s * s;
    }
#pragma unroll
    for (int off = 32; off >= 1; off >>= 1) ss += __shfl_xor(ss, off);
    if (writeResid) {
#pragma unroll
        for (int i = 0; i < 6; i++) resid[base + lane + i * 64] = v[i];
    }
    float sc = rsqrtf(ss * (1.f / 384.f) + 1e-5f);
#pragma unroll
    for (int i = 0; i < 6; i++) {
        int e = lane + i * 64;
        float o = v[i] * sc * wn[e];
        if constexpr (OBF)
            outb[base + e] = f2bf(o);
        else
            outf[base + e] = o;
    }
}

// ---------------- conv1d + silu -> xtb (bf16, [dir][b][t][d]) ----------------
__global__ __launch_bounds__(256) void k_conv(
    const unsigned short* __restrict__ xz,
    const float* __restrict__ cw_f, const float* __restrict__ cb_f,
    const float* __restrict__ cw_b, const float* __restrict__ cb_b,
    unsigned short* __restrict__ xtb) {
    const int tid = threadIdx.x;
    if (tid >= 192) return;
    const int b = blockIdx.y, dir = blockIdx.z;
    const float* cw = dir ? cw_b : cw_f;
    const float* cb = dir ? cb_b : cb_f;
    const int o = tid % 96, tg = tid / 96;
    const int t0 = blockIdx.x * 16 + tg * 8;
    const int d0 = o * 8;
    const size_t xzb = (size_t)b * LL * 1536;
    const size_t obase = ((size_t)dir * BB + b) * LL;

    f32x4 wq[8];
    float bv[8];
#pragma unroll
    for (int j = 0; j < 8; j++) {
        wq[j] = *(const f32x4*)&cw[(d0 + j) * 4];
        bv[j] = cb[d0 + j];
    }

    auto loadrow = [&](int t) -> u16x8 {
        if (t < 0) return (u16x8){0, 0, 0, 0, 0, 0, 0, 0};
        int phys = dir ? (LL - 1 - t) : t;
        return *(const u16x8*)&xz[xzb + (size_t)phys * 1536 + d0];
    };

    float f0[8], f1[8], f2[8];
    u16x8 v;
    v = loadrow(t0 - 3);
#pragma unroll
    for (int j = 0; j < 8; j++) f0[j] = bf2f(v[j]);
    v = loadrow(t0 - 2);
#pragma unroll
    for (int j = 0; j < 8; j++) f1[j] = bf2f(v[j]);
    v = loadrow(t0 - 1);
#pragma unroll
    for (int j = 0; j < 8; j++) f2[j] = bf2f(v[j]);

    for (int s = 0; s < 8; ++s) {
        int t = t0 + s;
        v = loadrow(t);
        float f3[8];
        u16x8 outv;
#pragma unroll
        for (int j = 0; j < 8; j++) {
            f3[j] = bf2f(v[j]);
            float cv = wq[j][0] * f0[j] + wq[j][1] * f1[j] + wq[j][2] * f2[j] + wq[j][3] * f3[j] + bv[j];
            outv[j] = f2bf(silu_f(cv));
        }
        *(u16x8*)&xtb[(obase + t) * 768 + d0] = outv;
#pragma unroll
        for (int j = 0; j < 8; j++) { f0[j] = f1[j]; f1[j] = f2[j]; f2[j] = f3[j]; }
    }
}

// ---------------- dbc GEMM: [12544 rows] x [64 cols] x K=768 -> dt_low / B / C ----------------
__global__ __launch_bounds__(256) void k_dbc(
    const unsigned short* __restrict__ xtb,
    const unsigned short* __restrict__ xpwb_f, const unsigned short* __restrict__ xpwb_b,
    unsigned short* __restrict__ dtlow, float* __restrict__ Bm, float* __restrict__ Cm) {
    const int tid = threadIdx.x;
    const int m0 = blockIdx.x * 64;
    const unsigned short* W = (m0 >= 6272) ? xpwb_b : xpwb_f;
    __shared__ unsigned short As[64 * 40];
    __shared__ unsigned short Ws[64 * 40];
    const int sr = tid >> 2, skc = tid & 3;
    const int lane = tid & 63, wv = tid >> 6;
    const int lr = lane & 15, kg = lane >> 4;

    f32x4 acc[4];
#pragma unroll
    for (int mi = 0; mi < 4; mi++) acc[mi] = (f32x4){0.f, 0.f, 0.f, 0.f};

    u16x8 ar, wr_;
    auto loadT = [&](int kt) {
        ar = *(const u16x8*)(xtb + (size_t)(m0 + sr) * 768 + kt * 32 + skc * 8);
        wr_ = *(const u16x8*)(W + (size_t)sr * 768 + kt * 32 + skc * 8);
    };
    loadT(0);
    for (int kt = 0; kt < 24; ++kt) {
        *(u16x8*)&As[sr * 40 + skc * 8] = ar;
        *(u16x8*)&Ws[sr * 40 + skc * 8] = wr_;
        __syncthreads();
        if (kt + 1 < 24) loadT(kt + 1);
        bf16x8 bfm = *(const bf16x8*)&Ws[(wv * 16 + lr) * 40 + kg * 8];
#pragma unroll
        for (int mi = 0; mi < 4; mi++) {
            bf16x8 af = *(const bf16x8*)&As[(mi * 16 + lr) * 40 + kg * 8];
            acc[mi] = __builtin_amdgcn_mfma_f32_16x16x32_bf16(af, bfm, acc[mi], 0, 0, 0);
        }
        __syncthreads();
    }
#pragma unroll
    for (int mi = 0; mi < 4; mi++)
#pragma unroll
        for (int j = 0; j < 4; j++) {
            int row = m0 + mi * 16 + kg * 4 + j;
            int cc = wv * 16 + lr;
            float vv = acc[mi][j];
            if (cc < 24) dtlow[(size_t)row * 32 + cc] = f2bf(vv);
            else if (cc < 40) Bm[(size_t)row * 16 + (cc - 24)] = vv;
            else if (cc < 56) Cm[(size_t)row * 16 + (cc - 40)] = vv;
            else dtlow[(size_t)row * 32 + (cc - 32)] = 0;
        }
}

// ---------------- chunked 2-pass selective scan: 2 d's per thread, 8 lane-pairs x 32 chunks ----------------
// 256 threads; grid (48,4,2) = 384 blocks; LDS 36.9 KB
__global__ __launch_bounds__(256) void k_scan(
    const unsigned short* __restrict__ xtb, const unsigned short* __restrict__ dtb,
    const unsigned short* __restrict__ xz,
    const float* __restrict__ Bmat, const float* __restrict__ Cmat,
    const float* __restrict__ Alog_f, const float* __restrict__ Alog_b,
    const float* __restrict__ Dp_f, const float* __restrict__ Dp_b,
    unsigned short* __restrict__ ybuf) {
    const int tid = threadIdx.x;
    const int dl = tid & 7, c = tid >> 3;  // 8 lane-pairs, 32 chunks
    const int d0 = blockIdx.x * 16 + dl * 2;
    const int b = blockIdx.y, dir = blockIdx.z;
    const float* Alog = dir ? Alog_b : Alog_f;
    const float* Dp = dir ? Dp_b : Dp_f;
    const int t0 = c * 49;

    __shared__ float Ssh[32][16][17];   // [chunk][d-local][n] (+1 pad)
    __shared__ float sdt_sh[32][16];

    float anA[16], anB[16];
#pragma unroll
    for (int n = 0; n < 16; n++) {
        anA[n] = -__expf(Alog[d0 * 16 + n]) * 1.44269504f;
        anB[n] = -__expf(Alog[(d0 + 1) * 16 + n]) * 1.44269504f;
    }
    bool unif = (anA[0] != 0.f) && (anB[0] != 0.f);
#pragma unroll
    for (int n = 1; n < 16; n++) {
        float rA = anA[n] / anA[0];
        float rB = anB[n] / anB[0];
        unif = unif && (fabsf(rA - (float)(n + 1)) < 1e-3f) && (fabsf(rB - (float)(n + 1)) < 1e-3f);
    }
    const float a0A = anA[0], a0B = anB[0];
    float DdA = Dp[d0], DdB = Dp[d0 + 1];

    const size_t dbase = ((size_t)dir * BB + b) * LL;
    const size_t rowb = dbase * 768 + d0;

    f32x2 SA[8], SB[8];
#pragma unroll
    for (int k = 0; k < 8; k++) { SA[k] = (f32x2){0.f, 0.f}; SB[k] = (f32x2){0.f, 0.f}; }
    float sumA = 0.f, sumB = 0.f;

    // ---- pass 1 ----
    for (int s = 0; s < 49; ++s) {
        int t = t0 + s;
        unsigned int xv = *(const unsigned int*)&xtb[rowb + (size_t)t * 768];
        unsigned int dv = *(const unsigned int*)&dtb[rowb + (size_t)t * 768];
        float xtA = bf2f((unsigned short)xv), xtB = bf2f((unsigned short)(xv >> 16));
        float dtA = bf2f((unsigned short)dv), dtB = bf2f((unsigned short)(dv >> 16));
        sumA += dtA; sumB += dtB;
        float dxA = dtA * xtA, dxB = dtB * xtB;
        const f32x4* Bp = (const f32x4*)(Bmat + (dbase + t) * 16);
        f32x4 Bq[4] = {Bp[0], Bp[1], Bp[2], Bp[3]};
        const f32x2* B2 = (const f32x2*)Bq;
        f32x2 dxA2 = {dxA, dxA}, dxB2 = {dxB, dxB};
        if (unif) {
            float pA = exp2_f(dtA * a0A), pB = exp2_f(dtB * a0B);
            float qA = pA * pA, qB = pB * pB;
            f32x2 qA2 = {qA, qA}, qB2 = {qB, qB};
            f32x2 pwA[8], pwB[8];
            pwA[0] = (f32x2){pA, qA};
            pwB[0] = (f32x2){pB, qB};
#pragma unroll
            for (int j = 1; j < 8; j++) { pwA[j] = pwA[j - 1] * qA2; pwB[j] = pwB[j - 1] * qB2; }
#pragma unroll
            for (int k = 0; k < 8; k++) {
                SA[k] = SA[k] * pwA[k] + dxA2 * B2[k];
                SB[k] = SB[k] * pwB[k] + dxB2 * B2[k];
            }
        } else {
#pragma unroll
            for (int n = 0; n < 16; n++) {
                float bqv = ((const float*)Bq)[n];
                float eA = exp2_f(dtA * anA[n]);
                float eB = exp2_f(dtB * anB[n]);
                SA[n >> 1][n & 1] = SA[n >> 1][n & 1] * eA + dxA * bqv;
                SB[n >> 1][n & 1] = SB[n >> 1][n & 1] * eB + dxB * bqv;
            }
        }
    }
#pragma unroll
    for (int n = 0; n < 16; n++) {
        Ssh[c][dl * 2][n] = SA[n >> 1][n & 1];
        Ssh[c][dl * 2 + 1][n] = SB[n >> 1][n & 1];
    }
    sdt_sh[c][dl * 2] = sumA;
    sdt_sh[c][dl * 2 + 1] = sumB;
    __syncthreads();

    // ---- combine: exclusive prefix over 32 chunks; 256 threads -> (d-local, n2) pairs ----
    {
        int cdl = tid & 15, n2 = tid >> 4;  // d-local 0..15, n 0..15
        float a_n = -__expf(Alog[(blockIdx.x * 16 + cdl) * 16 + n2]) * 1.44269504f;
        float H = 0.f;
#pragma unroll
        for (int c2 = 0; c2 < 32; c2++) {
            float P = exp2_f(a_n * sdt_sh[c2][cdl]);
            float tmp = Ssh[c2][cdl][n2];
            Ssh[c2][cdl][n2] = H;
            H = H * P + tmp;
        }
    }
    __syncthreads();

    // ---- pass 2 ----
#pragma unroll
    for (int n = 0; n < 16; n++) {
        SA[n >> 1][n & 1] = Ssh[c][dl * 2][n];
        SB[n >> 1][n & 1] = Ssh[c][dl * 2 + 1][n];
    }
    for (int s = 0; s < 49; ++s) {
        int t = t0 + s;
        unsigned int xv = *(const unsigned int*)&xtb[rowb + (size_t)t * 768];
        unsigned int dv = *(const unsigned int*)&dtb[rowb + (size_t)t * 768];
        float xtA = bf2f((unsigned short)xv), xtB = bf2f((unsigned short)(xv >> 16));
        float dtA = bf2f((unsigned short)dv), dtB = bf2f((unsigned short)(dv >> 16));
        float dxA = dtA * xtA, dxB = dtB * xtB;
        const f32x4* Bp = (const f32x4*)(Bmat + (dbase + t) * 16);
        f32x4 Bq[4] = {Bp[0], Bp[1], Bp[2], Bp[3]};
        const f32x4* Cp = (const f32x4*)(Cmat + (dbase + t) * 16);
        f32x4 Cq[4] = {Cp[0], Cp[1], Cp[2], Cp[3]};
        const f32x2* B2 = (const f32x2*)Bq;
        const f32x2* C2 = (const f32x2*)Cq;
        f32x2 dxA2 = {dxA, dxA}, dxB2 = {dxB, dxB};
        f32x2 yA2 = {0.f, 0.f}, yB2 = {0.f, 0.f};
        if (unif) {
            float pA = exp2_f(dtA * a0A), pB = exp2_f(dtB * a0B);
            float qA = pA * pA, qB = pB * pB;
            f32x2 qA2 = {qA, qA}, qB2 = {qB, qB};
            f32x2 pwA[8], pwB[8];
            pwA[0] = (f32x2){pA, qA};
            pwB[0] = (f32x2){pB, qB};
#pragma unroll
            for (int j = 1; j < 8; j++) { pwA[j] = pwA[j - 1] * qA2; pwB[j] = pwB[j - 1] * qB2; }
#pragma unroll
            for (int k = 0; k < 8; k++) {
                SA[k] = SA[k] * pwA[k] + dxA2 * B2[k];
                SB[k] = SB[k] * pwB[k] + dxB2 * B2[k];
                yA2 = yA2 + SA[k] * C2[k];
                yB2 = yB2 + SB[k] * C2[k];
            }
        } else {
#pragma unroll
            for (int n = 0; n < 16; n++) {
                float bqv = ((const float*)Bq)[n];
                float cqv = ((const float*)Cq)[n];
                float eA = exp2_f(dtA * anA[n]);
                float eB = exp2_f(dtB * anB[n]);
                float sA = SA[n >> 1][n & 1] * eA + dxA * bqv;
                float sB = SB[n >> 1][n & 1] * eB + dxB * bqv;
                SA[n >> 1][n & 1] = sA;
                SB[n >> 1][n & 1] = sB;
                yA2[n & 1] += sA * cqv;
                yB2[n & 1] += sB * cqv;
            }
        }
        float yA = yA2[0] + yA2[1] + xtA * DdA;
        float yB = yB2[0] + yB2[1] + xtB * DdB;
        int pt = dir ? (LL - 1 - t) : t;
        unsigned int zv2 = *(const unsigned int*)&xz[((size_t)b * LL + pt) * 1536 + 768 + d0];
        float zA = bf2f((unsigned short)zv2), zB = bf2f((unsigned short)(zv2 >> 16));
        unsigned int yo = (unsigned int)f2bf(yA * silu_f(zA)) |
                          ((unsigned int)f2bf(yB * silu_f(zB)) << 16);
        *(unsigned int*)&ybuf[rowb + (size_t)pt * 768] = yo;
    }
}

// ---------------- launcher ----------------
extern "C" void kernel_launch(void* const* d_in, const int* in_sizes, int n_in,
                              void* d_out, int out_size, void* d_ws, size_t ws_size,
                              hipStream_t stream) {
    const float* x        = (const float*)d_in[0];
    const float* patch_w  = (const float*)d_in[1];
    const float* patch_b  = (const float*)d_in[2];
    const float* pos_emb  = (const float*)d_in[3];
    const float* tpos     = (const float*)d_in[4];
    const float* imp_w1   = (const float*)d_in[5];
    const float* imp_b1   = (const float*)d_in[6];
    const float* imp_w2   = (const float*)d_in[7];
    const float* imp_b2   = (const float*)d_in[8];
    const float* in_w     = (const float*)d_in[9];
    const float* out_w    = (const float*)d_in[10];
    const float* norm_w   = (const float*)d_in[11];
    const float* norm_f_w = (const float*)d_in[12];
    const float* conv_w   = (const float*)d_in[13];
    const float* conv_b   = (const float*)d_in[14];
    const float* xp_w     = (const float*)d_in[15];
    const float* dt_w     = (const float*)d_in[16];
    const float* dt_b     = (const float*)d_in[17];
    const float* A_log    = (const float*)d_in[18];
    const float* Dp       = (const float*)d_in[19];
    const float* conv_w_b = (const float*)d_in[20];
    const float* conv_b_b = (const float*)d_in[21];
    const float* xp_w_b   = (const float*)d_in[22];
    const float* dt_w_b   = (const float*)d_in[23];
    const float* dt_b_b   = (const float*)d_in[24];
    const float* A_log_b  = (const float*)d_in[25];
    const float* D_b      = (const float*)d_in[26];

    float* out = (float*)d_out;
    float* logits_out = out + 2408448;

    char* wsb = (char*)d_ws;
    size_t off = 0;
    auto carve = [&](size_t bytes) { char* p = wsb + off; off += bytes; return p; };

    unsigned short* in_wb    = (unsigned short*)carve(28311552);  // 24*1536*384
    unsigned short* out_wb   = (unsigned short*)carve(14155776);  // 24*384*768
    unsigned short* patch_wb = (unsigned short*)carve(589824);
    unsigned short* imp_w1b  = (unsigned short*)carve(294912);
    unsigned short* xpwb_f   = (unsigned short*)carve(2359296);   // 24*64*768
    unsigned short* xpwb_b   = (unsigned short*)carve(2359296);
    unsigned short* dtwb_f   = (unsigned short*)carve(1179648);   // 24*768*32
    unsigned short* dtwb_b   = (unsigned short*)carve(1179648);
    unsigned short* hidden   = (unsigned short*)carve(4816896);   // 6272*384 bf16
    float*          resid    = (float*)carve(9633792);
    unsigned short* hn       = (unsigned short*)carve(4816896);
    unsigned short* xzb      = (unsigned short*)carve(19267584);  // 4*1568*1536 bf16
    unsigned short* xtb      = (unsigned short*)carve(19267584);  // 2*4*1568*768 bf16
    unsigned short* g_dt     = (unsigned short*)carve(19267584);
    unsigned short* dtlow    = (unsigned short*)carve(802816);    // 12544*32 bf16
    float*          Bm       = (float*)carve(802816);             // 12544*16 f32
    float*          Cm       = (float*)carve(802816);
    unsigned short* ybuf     = (unsigned short*)carve(19267584);

    float*          h1       = (float*)xtb;            // pre-loop only
    unsigned short* patches  = (unsigned short*)ybuf;  // pre-loop only

    // weight prep
    k_cvt<<<2048, 256, 0, stream>>>(in_w, in_wb, 3538944);
    k_cvt<<<2048, 256, 0, stream>>>(out_w, out_wb, 1769472);
    k_cvt<<<288, 256, 0, stream>>>(patch_w, patch_wb, 73728);
    k_cvt<<<144, 256, 0, stream>>>(imp_w1, imp_w1b, 36864);
    k_pad_xpw<<<1024, 256, 0, stream>>>(xp_w, xpwb_f);
    k_pad_xpw<<<1024, 256, 0, stream>>>(xp_w_b, xpwb_b);
    k_pad_dtw<<<1024, 256, 0, stream>>>(dt_w, dtwb_f);
    k_pad_dtw<<<1024, 256, 0, stream>>>(dt_w_b, dtwb_b);

    k_patch<<<6272, 256, 0, stream>>>(x, patches);
    k_gemm<1, false, true><<<dim3(3, 49), 256, 0, stream>>>(patches, nullptr, patch_wb, nullptr,
                                                            nullptr, hidden, 768, 384,
                                                            patch_b, nullptr, pos_emb, tpos);
    k_gemm<2, false, false><<<dim3(3, 49), 256, 0, stream>>>(hidden, nullptr, imp_w1b, nullptr,
                                                             h1, nullptr, 384, 384,
                                                             imp_b1, nullptr, nullptr, nullptr);
    k_logits<<<6272, 64, 0, stream>>>(h1, imp_w2, imp_b2, hidden, logits_out);

    for (int l = 0; l < 24; ++l) {
        k_norm<true><<<1568, 256, 0, stream>>>(hidden, resid, norm_w + l * 384, nullptr, hn,
                                               (l == 0) ? 1 : 0, 1);
        k_gemm<0, false, true><<<dim3(12, 49), 256, 0, stream>>>(hn, nullptr, in_wb + (size_t)l * 589824,
                                                                 nullptr, nullptr, xzb, 384, 1536,
                                                                 nullptr, nullptr, nullptr, nullptr);
        k_conv<<<dim3(98, 4, 2), 256, 0, stream>>>(xzb, conv_w + l * 3072, conv_b + l * 768,
                                                   conv_w_b + l * 3072, conv_b_b + l * 768, xtb);
        k_dbc<<<196, 256, 0, stream>>>(xtb, xpwb_f + (size_t)l * 49152, xpwb_b + (size_t)l * 49152,
                                       dtlow, Bm, Cm);
        k_gemm<3, false, true><<<dim3(6, 98), 256, 0, stream>>>(dtlow, nullptr,
                                                                dtwb_f + (size_t)l * 24576,
                                                                dtwb_b + (size_t)l * 24576,
                                                                nullptr, g_dt, 32, 768,
                                                                dt_b + l * 768, dt_b_b + l * 768,
                                                                nullptr, nullptr);
        k_scan<<<dim3(48, 4, 2), 256, 0, stream>>>(
            xtb, g_dt, xzb, Bm, Cm,
            A_log + l * 12288, A_log_b + l * 12288,
            Dp + l * 768, D_b + l * 768,
            ybuf);
        k_gemm<0, true, true><<<dim3(3, 49), 256, 0, stream>>>(ybuf, ybuf + 4816896,
                                                               out_wb + (size_t)l * 294912, nullptr,
                                                               nullptr, hidden, 768, 384,
                                                               nullptr, nullptr, nullptr, nullptr);
    }
    k_norm<false><<<1568, 256, 0, stream>>>(hidden, resid, norm_f_w, out, nullptr, 0, 0);
}

// Round 19
// 4884.949 us; speedup vs baseline: 1.0381x; 1.0381x over previous
//
#include <hip/hip_runtime.h>
#include <hip/hip_bf16.h>

#define LL 1568
#define EE 384
#define DD 768
#define BB 4

typedef float f32x4 __attribute__((ext_vector_type(4)));
typedef float f32x2 __attribute__((ext_vector_type(2)));
typedef unsigned short u16x2 __attribute__((ext_vector_type(2)));
typedef unsigned short u16x4 __attribute__((ext_vector_type(4)));
typedef unsigned short u16x8 __attribute__((ext_vector_type(8)));
typedef __bf16 bf16x8 __attribute__((ext_vector_type(8)));

__device__ inline unsigned short f2bf(float f) {
    unsigned int u = __builtin_bit_cast(unsigned int, f);
    u += 0x7fffu + ((u >> 16) & 1u);
    return (unsigned short)(u >> 16);
}
__device__ inline float bf2f(unsigned short u) {
    unsigned int v = ((unsigned int)u) << 16;
    return __builtin_bit_cast(float, v);
}
__device__ inline float silu_f(float v) { return v / (1.f + __expf(-v)); }
__device__ inline float exp2_f(float v) { return __builtin_amdgcn_exp2f(v); }

// ---------------- weight fp32 -> bf16 ----------------
__global__ __launch_bounds__(256) void k_cvt(const float* __restrict__ src,
                                             unsigned short* __restrict__ dst, int n4) {
    int i = blockIdx.x * 256 + threadIdx.x;
    int stride = gridDim.x * 256;
    for (; i < n4; i += stride) {
        f32x4 v = *(const f32x4*)(src + (size_t)i * 4);
        u16x4 o;
#pragma unroll
        for (int j = 0; j < 4; j++) o[j] = f2bf(v[j]);
        *(u16x4*)(dst + (size_t)i * 4) = o;
    }
}

// xpw [24][56][768] f32 -> [24][64][768] bf16 (rows 56..63 zero)
__global__ __launch_bounds__(256) void k_pad_xpw(const float* __restrict__ src,
                                                 unsigned short* __restrict__ dst) {
    const int total = 24 * 64 * 768;
    for (int i = blockIdx.x * 256 + threadIdx.x; i < total; i += gridDim.x * 256) {
        int l = i / (64 * 768);
        int r = (i / 768) % 64;
        int dcol = i % 768;
        dst[i] = (r < 56) ? f2bf(src[((size_t)l * 56 + r) * 768 + dcol]) : (unsigned short)0;
    }
}

// dtw [24][768][24] f32 -> [24][768][32] bf16 (cols 24..31 zero)
__global__ __launch_bounds__(256) void k_pad_dtw(const float* __restrict__ src,
                                                 unsigned short* __restrict__ dst) {
    const int total = 24 * 768 * 32;
    for (int i = blockIdx.x * 256 + threadIdx.x; i < total; i += gridDim.x * 256) {
        int kk = i & 31;
        int nrow = i >> 5;
        dst[i] = (kk < 24) ? f2bf(src[(size_t)nrow * 24 + kk]) : (unsigned short)0;
    }
}

// ---------------- patch extraction (bf16 out) ----------------
__global__ __launch_bounds__(256) void k_patch(const float* __restrict__ x,
                                               unsigned short* __restrict__ patches) {
    int bid = blockIdx.x;
    int b = bid / LL, rr = bid % LL, t = rr / 196, pp = rr % 196, hp = pp / 14, wp = pp % 14;
    for (int k = threadIdx.x; k < 768; k += 256) {
        int c = k >> 8, rem = k & 255, i = rem >> 4, j = rem & 15;
        patches[(size_t)bid * 768 + k] =
            f2bf(x[(((size_t)(b * 3 + c) * 8 + t) * 224 + hp * 16 + i) * 224 + wp * 16 + j]);
    }
}

// ---------------- GEMM: C[m][n] = sum_k A[m][k] * W[n][k]  (bf16 in, MFMA) ----------------
// EPI: 0 none, 1 patch-add (bf16 Cb), 2 bias+relu (f32), 3 bias+softplus (bf16, dual-dir W)
// MTILE/NTILE: output tile (rows/cols); 4 waves arranged 2x2 over the tile
template <int EPI, bool ASUM, bool OUTBF, int MTILE = 128, int NTILE = 128>
__global__ __launch_bounds__(256) void k_gemm(
    const unsigned short* __restrict__ A, const unsigned short* __restrict__ A2,
    const unsigned short* __restrict__ W, const unsigned short* __restrict__ W2,
    float* __restrict__ C, unsigned short* __restrict__ Cb, int K, int ldc,
    const float* __restrict__ bias, const float* __restrict__ bias2,
    const float* __restrict__ pos, const float* __restrict__ tpos) {
    const int tid = threadIdx.x;
    const int m0 = blockIdx.y * MTILE;
    const int n0 = blockIdx.x * NTILE;
    constexpr int MFRAG = MTILE / 32;       // m-fragments per wave
    constexpr int NFRAG = NTILE / 32;       // n-fragments per wave
    constexpr int ALOAD = MTILE / 64;
    constexpr int WLOAD = NTILE / 64;
    __shared__ unsigned short As[MTILE * 40];
    __shared__ unsigned short Ws[NTILE * 40];
    const int sr = tid >> 2;
    const int skc = tid & 3;

    const unsigned short* Wp = W;
    const float* biasp = bias;
    if constexpr (EPI == 3) {
        if (m0 >= 6272) { Wp = W2; biasp = bias2; }
    }

    f32x4 acc[MFRAG][NFRAG];
#pragma unroll
    for (int mi = 0; mi < MFRAG; mi++)
#pragma unroll
        for (int ni = 0; ni < NFRAG; ni++) acc[mi][ni] = (f32x4){0.f, 0.f, 0.f, 0.f};

    const int lane = tid & 63;
    const int wv = tid >> 6;
    const int wm = (wv & 1) * (MTILE / 2);
    const int wn = (wv >> 1) * (NTILE / 2);
    const int lr = lane & 15;
    const int kg = lane >> 4;

    u16x8 ar[ALOAD], wr_[WLOAD];
    auto loadT = [&](int kt) {
#pragma unroll
        for (int i = 0; i < ALOAD; i++) {
            size_t ka = (size_t)(m0 + sr + 64 * i) * K + kt * 32 + skc * 8;
            u16x8 v = *(const u16x8*)(A + ka);
            if constexpr (ASUM) {
                u16x8 v2 = *(const u16x8*)(A2 + ka);
#pragma unroll
                for (int j = 0; j < 8; j++) v[j] = f2bf(bf2f(v[j]) + bf2f(v2[j]));
            }
            ar[i] = v;
        }
#pragma unroll
        for (int i = 0; i < WLOAD; i++)
            wr_[i] = *(const u16x8*)(Wp + (size_t)(n0 + sr + 64 * i) * K + kt * 32 + skc * 8);
    };

    const int nK = K >> 5;
    loadT(0);
    for (int kt = 0; kt < nK; ++kt) {
#pragma unroll
        for (int i = 0; i < ALOAD; i++)
            *(u16x8*)&As[(sr + 64 * i) * 40 + skc * 8] = ar[i];
#pragma unroll
        for (int i = 0; i < WLOAD; i++)
            *(u16x8*)&Ws[(sr + 64 * i) * 40 + skc * 8] = wr_[i];
        __syncthreads();
        if (kt + 1 < nK) loadT(kt + 1);
        bf16x8 af[MFRAG], bfm[NFRAG];
#pragma unroll
        for (int mi = 0; mi < MFRAG; mi++)
            af[mi] = *(const bf16x8*)&As[(wm + mi * 16 + lr) * 40 + kg * 8];
#pragma unroll
        for (int ni = 0; ni < NFRAG; ni++)
            bfm[ni] = *(const bf16x8*)&Ws[(wn + ni * 16 + lr) * 40 + kg * 8];
#pragma unroll
        for (int mi = 0; mi < MFRAG; mi++)
#pragma unroll
            for (int ni = 0; ni < NFRAG; ni++)
                acc[mi][ni] = __builtin_amdgcn_mfma_f32_16x16x32_bf16(af[mi], bfm[ni], acc[mi][ni], 0, 0, 0);
        __syncthreads();
    }

#pragma unroll
    for (int mi = 0; mi < MFRAG; mi++)
#pragma unroll
        for (int ni = 0; ni < NFRAG; ni++)
#pragma unroll
            for (int j = 0; j < 4; j++) {
                int m = m0 + wm + mi * 16 + kg * 4 + j;
                int n = n0 + wn + ni * 16 + lr;
                float v = acc[mi][ni][j];
                if constexpr (EPI == 1) {
                    int rr = m % LL;
                    int t = rr / 196, p = rr % 196;
                    v += bias[n] + pos[p * EE + n] + tpos[t * EE + n];
                    Cb[(size_t)m * ldc + n] = f2bf(v);
                } else if constexpr (EPI == 2) {
                    v += bias[n];
                    v = fmaxf(v, 0.f);
                    C[(size_t)m * ldc + n] = v;
                } else if constexpr (EPI == 3) {
                    v += biasp[n];
                    float sp = (v > 20.f) ? v : log1pf(__expf(v));
                    Cb[(size_t)m * ldc + n] = f2bf(sp);
                } else {
                    if constexpr (OUTBF)
                        Cb[(size_t)m * ldc + n] = f2bf(v);
                    else
                        C[(size_t)m * ldc + n] = v;
                }
            }
}

// ---------------- importance logits + sigmoid scale (bf16 hidden in-place) ----------------
__global__ __launch_bounds__(64) void k_logits(const float* __restrict__ h1, const float* __restrict__ w2,
                                               const float* __restrict__ b2,
                                               unsigned short* __restrict__ xseq,
                                               float* __restrict__ logits_out) {
    int row = blockIdx.x;
    int lane = threadIdx.x;
    float acc = 0.f;
#pragma unroll
    for (int i = 0; i < 6; i++) {
        int e = lane + i * 64;
        acc += h1[(size_t)row * EE + e] * w2[e];
    }
#pragma unroll
    for (int off = 32; off >= 1; off >>= 1) acc += __shfl_xor(acc, off);
    float logit = acc + b2[0];
    if (lane == 0) logits_out[row] = logit;
    float sg = 1.f / (1.f + __expf(-logit));
#pragma unroll
    for (int i = 0; i < 6; i++) {
        int e = lane + i * 64;
        size_t idx = (size_t)row * EE + e;
        xseq[idx] = f2bf(bf2f(xseq[idx]) * sg);
    }
}

// ---------------- residual add + rmsnorm (bf16 hidden, f32 resid) ----------------
template <bool OBF>
__global__ __launch_bounds__(256) void k_norm(const unsigned short* __restrict__ hidden,
                                              float* __restrict__ resid,
                                              const float* __restrict__ wn, float* __restrict__ outf,
                                              unsigned short* __restrict__ outb,
                                              int first, int writeResid) {
    int row = blockIdx.x * 4 + (threadIdx.x >> 6);
    int lane = threadIdx.x & 63;
    size_t base = (size_t)row * EE;
    float v[6];
    float ss = 0.f;
#pragma unroll
    for (int i = 0; i < 6; i++) {
        int e = lane + i * 64;
        float h = bf2f(hidden[base + e]);
        float r = first ? 0.f : resid[base + e];
        float s = h + r;
        v[i] = s;
        ss += s * s;
    }
#pragma unroll
    for (int off = 32; off >= 1; off >>= 1) ss += __shfl_xor(ss, off);
    if (writeResid) {
#pragma unroll
        for (int i = 0; i < 6; i++) resid[base + lane + i * 64] = v[i];
    }
    float sc = rsqrtf(ss * (1.f / 384.f) + 1e-5f);
#pragma unroll
    for (int i = 0; i < 6; i++) {
        int e = lane + i * 64;
        float o = v[i] * sc * wn[e];
        if constexpr (OBF)
            outb[base + e] = f2bf(o);
        else
            outf[base + e] = o;
    }
}

// ---------------- conv1d + silu -> xtb (bf16, [dir][b][t][d]) ----------------
__global__ __launch_bounds__(256) void k_conv(
    const unsigned short* __restrict__ xz,
    const float* __restrict__ cw_f, const float* __restrict__ cb_f,
    const float* __restrict__ cw_b, const float* __restrict__ cb_b,
    unsigned short* __restrict__ xtb) {
    const int tid = threadIdx.x;
    if (tid >= 192) return;
    const int b = blockIdx.y, dir = blockIdx.z;
    const float* cw = dir ? cw_b : cw_f;
    const float* cb = dir ? cb_b : cb_f;
    const int o = tid % 96, tg = tid / 96;
    const int t0 = blockIdx.x * 16 + tg * 8;
    const int d0 = o * 8;
    const size_t xzb = (size_t)b * LL * 1536;
    const size_t obase = ((size_t)dir * BB + b) * LL;

    f32x4 wq[8];
    float bv[8];
#pragma unroll
    for (int j = 0; j < 8; j++) {
        wq[j] = *(const f32x4*)&cw[(d0 + j) * 4];
        bv[j] = cb[d0 + j];
    }

    auto loadrow = [&](int t) -> u16x8 {
        if (t < 0) return (u16x8){0, 0, 0, 0, 0, 0, 0, 0};
        int phys = dir ? (LL - 1 - t) : t;
        return *(const u16x8*)&xz[xzb + (size_t)phys * 1536 + d0];
    };

    float f0[8], f1[8], f2[8];
    u16x8 v;
    v = loadrow(t0 - 3);
#pragma unroll
    for (int j = 0; j < 8; j++) f0[j] = bf2f(v[j]);
    v = loadrow(t0 - 2);
#pragma unroll
    for (int j = 0; j < 8; j++) f1[j] = bf2f(v[j]);
    v = loadrow(t0 - 1);
#pragma unroll
    for (int j = 0; j < 8; j++) f2[j] = bf2f(v[j]);

    for (int s = 0; s < 8; ++s) {
        int t = t0 + s;
        v = loadrow(t);
        float f3[8];
        u16x8 outv;
#pragma unroll
        for (int j = 0; j < 8; j++) {
            f3[j] = bf2f(v[j]);
            float cv = wq[j][0] * f0[j] + wq[j][1] * f1[j] + wq[j][2] * f2[j] + wq[j][3] * f3[j] + bv[j];
            outv[j] = f2bf(silu_f(cv));
        }
        *(u16x8*)&xtb[(obase + t) * 768 + d0] = outv;
#pragma unroll
        for (int j = 0; j < 8; j++) { f0[j] = f1[j]; f1[j] = f2[j]; f2[j] = f3[j]; }
    }
}

// ---------------- dbc GEMM: [12544 rows] x [64 cols] x K=768 -> dt_low / B / C ----------------
__global__ __launch_bounds__(256) void k_dbc(
    const unsigned short* __restrict__ xtb,
    const unsigned short* __restrict__ xpwb_f, const unsigned short* __restrict__ xpwb_b,
    unsigned short* __restrict__ dtlow, float* __restrict__ Bm, float* __restrict__ Cm) {
    const int tid = threadIdx.x;
    const int m0 = blockIdx.x * 64;
    const unsigned short* W = (m0 >= 6272) ? xpwb_b : xpwb_f;
    __shared__ unsigned short As[64 * 40];
    __shared__ unsigned short Ws[64 * 40];
    const int sr = tid >> 2, skc = tid & 3;
    const int lane = tid & 63, wv = tid >> 6;
    const int lr = lane & 15, kg = lane >> 4;

    f32x4 acc[4];
#pragma unroll
    for (int mi = 0; mi < 4; mi++) acc[mi] = (f32x4){0.f, 0.f, 0.f, 0.f};

    u16x8 ar, wr_;
    auto loadT = [&](int kt) {
        ar = *(const u16x8*)(xtb + (size_t)(m0 + sr) * 768 + kt * 32 + skc * 8);
        wr_ = *(const u16x8*)(W + (size_t)sr * 768 + kt * 32 + skc * 8);
    };
    loadT(0);
    for (int kt = 0; kt < 24; ++kt) {
        *(u16x8*)&As[sr * 40 + skc * 8] = ar;
        *(u16x8*)&Ws[sr * 40 + skc * 8] = wr_;
        __syncthreads();
        if (kt + 1 < 24) loadT(kt + 1);
        bf16x8 bfm = *(const bf16x8*)&Ws[(wv * 16 + lr) * 40 + kg * 8];
#pragma unroll
        for (int mi = 0; mi < 4; mi++) {
            bf16x8 af = *(const bf16x8*)&As[(mi * 16 + lr) * 40 + kg * 8];
            acc[mi] = __builtin_amdgcn_mfma_f32_16x16x32_bf16(af, bfm, acc[mi], 0, 0, 0);
        }
        __syncthreads();
    }
#pragma unroll
    for (int mi = 0; mi < 4; mi++)
#pragma unroll
        for (int j = 0; j < 4; j++) {
            int row = m0 + mi * 16 + kg * 4 + j;
            int cc = wv * 16 + lr;
            float vv = acc[mi][j];
            if (cc < 24) dtlow[(size_t)row * 32 + cc] = f2bf(vv);
            else if (cc < 40) Bm[(size_t)row * 16 + (cc - 24)] = vv;
            else if (cc < 56) Cm[(size_t)row * 16 + (cc - 40)] = vv;
            else dtlow[(size_t)row * 32 + (cc - 32)] = 0;
        }
}

// ---------------- chunked 2-pass selective scan: 2 d's per thread (shared B/C), 32 chunks of 49 ----------------
// 512 threads = 16 dlane-pairs x 32 chunks; grid (24,4,2)
__global__ __launch_bounds__(512) void k_scan(
    const unsigned short* __restrict__ xtb, const unsigned short* __restrict__ dtb,
    const unsigned short* __restrict__ xz,
    const float* __restrict__ Bmat, const float* __restrict__ Cmat,
    const float* __restrict__ Alog_f, const float* __restrict__ Alog_b,
    const float* __restrict__ Dp_f, const float* __restrict__ Dp_b,
    unsigned short* __restrict__ ybuf) {
    const int tid = threadIdx.x;
    const int dl = tid & 15, c = tid >> 4;  // 16 lane-pairs, 32 chunks
    const int d0 = blockIdx.x * 32 + dl * 2;
    const int b = blockIdx.y, dir = blockIdx.z;
    const float* Alog = dir ? Alog_b : Alog_f;
    const float* Dp = dir ? Dp_b : Dp_f;
    const int t0 = c * 49;

    __shared__ float Ssh[32][32][17];   // [chunk][d-local][n] (+1 pad)
    __shared__ float sdt_sh[32][32];

    float anA[16], anB[16];
#pragma unroll
    for (int n = 0; n < 16; n++) {
        anA[n] = -__expf(Alog[d0 * 16 + n]) * 1.44269504f;
        anB[n] = -__expf(Alog[(d0 + 1) * 16 + n]) * 1.44269504f;
    }
    bool unif = (anA[0] != 0.f) && (anB[0] != 0.f);
#pragma unroll
    for (int n = 1; n < 16; n++) {
        float rA = anA[n] / anA[0];
        float rB = anB[n] / anB[0];
        unif = unif && (fabsf(rA - (float)(n + 1)) < 1e-3f) && (fabsf(rB - (float)(n + 1)) < 1e-3f);
    }
    const float a0A = anA[0], a0B = anB[0];
    float DdA = Dp[d0], DdB = Dp[d0 + 1];

    const size_t dbase = ((size_t)dir * BB + b) * LL;
    const size_t rowb = dbase * 768 + d0;

    f32x2 SA[8], SB[8];
#pragma unroll
    for (int k = 0; k < 8; k++) { SA[k] = (f32x2){0.f, 0.f}; SB[k] = (f32x2){0.f, 0.f}; }
    float sumA = 0.f, sumB = 0.f;

    // ---- pass 1 ----
    for (int s = 0; s < 49; ++s) {
        int t = t0 + s;
        unsigned int xv = *(const unsigned int*)&xtb[rowb + (size_t)t * 768];
        unsigned int dv = *(const unsigned int*)&dtb[rowb + (size_t)t * 768];
        float xtA = bf2f((unsigned short)xv), xtB = bf2f((unsigned short)(xv >> 16));
        float dtA = bf2f((unsigned short)dv), dtB = bf2f((unsigned short)(dv >> 16));
        sumA += dtA; sumB += dtB;
        float dxA = dtA * xtA, dxB = dtB * xtB;
        const f32x4* Bp = (const f32x4*)(Bmat + (dbase + t) * 16);
        f32x4 Bq[4] = {Bp[0], Bp[1], Bp[2], Bp[3]};
        const f32x2* B2 = (const f32x2*)Bq;
        f32x2 dxA2 = {dxA, dxA}, dxB2 = {dxB, dxB};
        if (unif) {
            float pA = exp2_f(dtA * a0A), pB = exp2_f(dtB * a0B);
            float qA = pA * pA, qB = pB * pB;
            f32x2 qA2 = {qA, qA}, qB2 = {qB, qB};
            f32x2 pwA[8], pwB[8];
            pwA[0] = (f32x2){pA, qA};
            pwB[0] = (f32x2){pB, qB};
#pragma unroll
            for (int j = 1; j < 8; j++) { pwA[j] = pwA[j - 1] * qA2; pwB[j] = pwB[j - 1] * qB2; }
#pragma unroll
            for (int k = 0; k < 8; k++) {
                SA[k] = SA[k] * pwA[k] + dxA2 * B2[k];
                SB[k] = SB[k] * pwB[k] + dxB2 * B2[k];
            }
        } else {
#pragma unroll
            for (int n = 0; n < 16; n++) {
                float bqv = ((const float*)Bq)[n];
                float eA = exp2_f(dtA * anA[n]);
                float eB = exp2_f(dtB * anB[n]);
                SA[n >> 1][n & 1] = SA[n >> 1][n & 1] * eA + dxA * bqv;
                SB[n >> 1][n & 1] = SB[n >> 1][n & 1] * eB + dxB * bqv;
            }
        }
    }
#pragma unroll
    for (int n = 0; n < 16; n++) {
        Ssh[c][dl * 2][n] = SA[n >> 1][n & 1];
        Ssh[c][dl * 2 + 1][n] = SB[n >> 1][n & 1];
    }
    sdt_sh[c][dl * 2] = sumA;
    sdt_sh[c][dl * 2 + 1] = sumB;
    __syncthreads();

    // ---- combine: exclusive prefix over 32 chunks; 512 threads -> (d-local, n2) pairs ----
    {
        int cdl = tid & 31, n2 = tid >> 5;  // d-local 0..31, n 0..15
        float a_n = -__expf(Alog[(blockIdx.x * 32 + cdl) * 16 + n2]) * 1.44269504f;
        float H = 0.f;
#pragma unroll
        for (int c2 = 0; c2 < 32; c2++) {
            float P = exp2_f(a_n * sdt_sh[c2][cdl]);
            float tmp = Ssh[c2][cdl][n2];
            Ssh[c2][cdl][n2] = H;
            H = H * P + tmp;
        }
    }
    __syncthreads();

    // ---- pass 2 ----
#pragma unroll
    for (int n = 0; n < 16; n++) {
        SA[n >> 1][n & 1] = Ssh[c][dl * 2][n];
        SB[n >> 1][n & 1] = Ssh[c][dl * 2 + 1][n];
    }
    for (int s = 0; s < 49; ++s) {
        int t = t0 + s;
        unsigned int xv = *(const unsigned int*)&xtb[rowb + (size_t)t * 768];
        unsigned int dv = *(const unsigned int*)&dtb[rowb + (size_t)t * 768];
        float xtA = bf2f((unsigned short)xv), xtB = bf2f((unsigned short)(xv >> 16));
        float dtA = bf2f((unsigned short)dv), dtB = bf2f((unsigned short)(dv >> 16));
        float dxA = dtA * xtA, dxB = dtB * xtB;
        const f32x4* Bp = (const f32x4*)(Bmat + (dbase + t) * 16);
        f32x4 Bq[4] = {Bp[0], Bp[1], Bp[2], Bp[3]};
        const f32x4* Cp = (const f32x4*)(Cmat + (dbase + t) * 16);
        f32x4 Cq[4] = {Cp[0], Cp[1], Cp[2], Cp[3]};
        const f32x2* B2 = (const f32x2*)Bq;
        const f32x2* C2 = (const f32x2*)Cq;
        f32x2 dxA2 = {dxA, dxA}, dxB2 = {dxB, dxB};
        f32x2 yA2 = {0.f, 0.f}, yB2 = {0.f, 0.f};
        if (unif) {
            float pA = exp2_f(dtA * a0A), pB = exp2_f(dtB * a0B);
            float qA = pA * pA, qB = pB * pB;
            f32x2 qA2 = {qA, qA}, qB2 = {qB, qB};
            f32x2 pwA[8], pwB[8];
            pwA[0] = (f32x2){pA, qA};
            pwB[0] = (f32x2){pB, qB};
#pragma unroll
            for (int j = 1; j < 8; j++) { pwA[j] = pwA[j - 1] * qA2; pwB[j] = pwB[j - 1] * qB2; }
#pragma unroll
            for (int k = 0; k < 8; k++) {
                SA[k] = SA[k] * pwA[k] + dxA2 * B2[k];
                SB[k] = SB[k] * pwB[k] + dxB2 * B2[k];
                yA2 = yA2 + SA[k] * C2[k];
                yB2 = yB2 + SB[k] * C2[k];
            }
        } else {
#pragma unroll
            for (int n = 0; n < 16; n++) {
                float bqv = ((const float*)Bq)[n];
                float cqv = ((const float*)Cq)[n];
                float eA = exp2_f(dtA * anA[n]);
                float eB = exp2_f(dtB * anB[n]);
                float sA = SA[n >> 1][n & 1] * eA + dxA * bqv;
                float sB = SB[n >> 1][n & 1] * eB + dxB * bqv;
                SA[n >> 1][n & 1] = sA;
                SB[n >> 1][n & 1] = sB;
                yA2[n & 1] += sA * cqv;
                yB2[n & 1] += sB * cqv;
            }
        }
        float yA = yA2[0] + yA2[1] + xtA * DdA;
        float yB = yB2[0] + yB2[1] + xtB * DdB;
        int pt = dir ? (LL - 1 - t) : t;
        unsigned int zv2 = *(const unsigned int*)&xz[((size_t)b * LL + pt) * 1536 + 768 + d0];
        float zA = bf2f((unsigned short)zv2), zB = bf2f((unsigned short)(zv2 >> 16));
        unsigned int yo = (unsigned int)f2bf(yA * silu_f(zA)) |
                          ((unsigned int)f2bf(yB * silu_f(zB)) << 16);
        *(unsigned int*)&ybuf[rowb + (size_t)pt * 768] = yo;
    }
}

// ---------------- launcher ----------------
extern "C" void kernel_launch(void* const* d_in, const int* in_sizes, int n_in,
                              void* d_out, int out_size, void* d_ws, size_t ws_size,
                              hipStream_t stream) {
    const float* x        = (const float*)d_in[0];
    const float* patch_w  = (const float*)d_in[1];
    const float* patch_b  = (const float*)d_in[2];
    const float* pos_emb  = (const float*)d_in[3];
    const float* tpos     = (const float*)d_in[4];
    const float* imp_w1   = (const float*)d_in[5];
    const float* imp_b1   = (const float*)d_in[6];
    const float* imp_w2   = (const float*)d_in[7];
    const float* imp_b2   = (const float*)d_in[8];
    const float* in_w     = (const float*)d_in[9];
    const float* out_w    = (const float*)d_in[10];
    const float* norm_w   = (const float*)d_in[11];
    const float* norm_f_w = (const float*)d_in[12];
    const float* conv_w   = (const float*)d_in[13];
    const float* conv_b   = (const float*)d_in[14];
    const float* xp_w     = (const float*)d_in[15];
    const float* dt_w     = (const float*)d_in[16];
    const float* dt_b     = (const float*)d_in[17];
    const float* A_log    = (const float*)d_in[18];
    const float* Dp       = (const float*)d_in[19];
    const float* conv_w_b = (const float*)d_in[20];
    const float* conv_b_b = (const float*)d_in[21];
    const float* xp_w_b   = (const float*)d_in[22];
    const float* dt_w_b   = (const float*)d_in[23];
    const float* dt_b_b   = (const float*)d_in[24];
    const float* A_log_b  = (const float*)d_in[25];
    const float* D_b      = (const float*)d_in[26];

    float* out = (float*)d_out;
    float* logits_out = out + 2408448;

    char* wsb = (char*)d_ws;
    size_t off = 0;
    auto carve = [&](size_t bytes) { char* p = wsb + off; off += bytes; return p; };

    unsigned short* in_wb    = (unsigned short*)carve(28311552);  // 24*1536*384
    unsigned short* out_wb   = (unsigned short*)carve(14155776);  // 24*384*768
    unsigned short* patch_wb = (unsigned short*)carve(589824);
    unsigned short* imp_w1b  = (unsigned short*)carve(294912);
    unsigned short* xpwb_f   = (unsigned short*)carve(2359296);   // 24*64*768
    unsigned short* xpwb_b   = (unsigned short*)carve(2359296);
    unsigned short* dtwb_f   = (unsigned short*)carve(1179648);   // 24*768*32
    unsigned short* dtwb_b   = (unsigned short*)carve(1179648);
    unsigned short* hidden   = (unsigned short*)carve(4816896);   // 6272*384 bf16
    float*          resid    = (float*)carve(9633792);
    unsigned short* hn       = (unsigned short*)carve(4816896);
    unsigned short* xzb      = (unsigned short*)carve(19267584);  // 4*1568*1536 bf16
    unsigned short* xtb      = (unsigned short*)carve(19267584);  // 2*4*1568*768 bf16
    unsigned short* g_dt     = (unsigned short*)carve(19267584);
    unsigned short* dtlow    = (unsigned short*)carve(802816);    // 12544*32 bf16
    float*          Bm       = (float*)carve(802816);             // 12544*16 f32
    float*          Cm       = (float*)carve(802816);
    unsigned short* ybuf     = (unsigned short*)carve(19267584);

    float*          h1       = (float*)xtb;            // pre-loop only
    unsigned short* patches  = (unsigned short*)ybuf;  // pre-loop only

    // weight prep
    k_cvt<<<2048, 256, 0, stream>>>(in_w, in_wb, 3538944);
    k_cvt<<<2048, 256, 0, stream>>>(out_w, out_wb, 1769472);
    k_cvt<<<288, 256, 0, stream>>>(patch_w, patch_wb, 73728);
    k_cvt<<<144, 256, 0, stream>>>(imp_w1, imp_w1b, 36864);
    k_pad_xpw<<<1024, 256, 0, stream>>>(xp_w, xpwb_f);
    k_pad_xpw<<<1024, 256, 0, stream>>>(xp_w_b, xpwb_b);
    k_pad_dtw<<<1024, 256, 0, stream>>>(dt_w, dtwb_f);
    k_pad_dtw<<<1024, 256, 0, stream>>>(dt_w_b, dtwb_b);

    k_patch<<<6272, 256, 0, stream>>>(x, patches);
    k_gemm<1, false, true><<<dim3(3, 49), 256, 0, stream>>>(patches, nullptr, patch_wb, nullptr,
                                                            nullptr, hidden, 768, 384,
                                                            patch_b, nullptr, pos_emb, tpos);
    k_gemm<2, false, false><<<dim3(3, 49), 256, 0, stream>>>(hidden, nullptr, imp_w1b, nullptr,
                                                             h1, nullptr, 384, 384,
                                                             imp_b1, nullptr, nullptr, nullptr);
    k_logits<<<6272, 64, 0, stream>>>(h1, imp_w2, imp_b2, hidden, logits_out);

    for (int l = 0; l < 24; ++l) {
        k_norm<true><<<1568, 256, 0, stream>>>(hidden, resid, norm_w + l * 384, nullptr, hn,
                                               (l == 0) ? 1 : 0, 1);
        k_gemm<0, false, true><<<dim3(12, 49), 256, 0, stream>>>(hn, nullptr, in_wb + (size_t)l * 589824,
                                                                 nullptr, nullptr, xzb, 384, 1536,
                                                                 nullptr, nullptr, nullptr, nullptr);
        k_conv<<<dim3(98, 4, 2), 256, 0, stream>>>(xzb, conv_w + l * 3072, conv_b + l * 768,
                                                   conv_w_b + l * 3072, conv_b_b + l * 768, xtb);
        k_dbc<<<196, 256, 0, stream>>>(xtb, xpwb_f + (size_t)l * 49152, xpwb_b + (size_t)l * 49152,
                                       dtlow, Bm, Cm);
        k_gemm<3, false, true><<<dim3(6, 98), 256, 0, stream>>>(dtlow, nullptr,
                                                                dtwb_f + (size_t)l * 24576,
                                                                dtwb_b + (size_t)l * 24576,
                                                                nullptr, g_dt, 32, 768,
                                                                dt_b + l * 768, dt_b_b + l * 768,
                                                                nullptr, nullptr);
        k_scan<<<dim3(24, 4, 2), 512, 0, stream>>>(
            xtb, g_dt, xzb, Bm, Cm,
            A_log + l * 12288, A_log_b + l * 12288,
            Dp + l * 768, D_b + l * 768,
            ybuf);
        // out-proj: M-split tiles (64x128) -> 294 blocks
        k_gemm<0, true, true, 64, 128><<<dim3(3, 98), 256, 0, stream>>>(ybuf, ybuf + 4816896,
                                                                        out_wb + (size_t)l * 294912, nullptr,
                                                                        nullptr, hidden, 768, 384,
                                                                        nullptr, nullptr, nullptr, nullptr);
    }
    k_norm<false><<<1568, 256, 0, stream>>>(hidden, resid, norm_f_w, out, nullptr, 0, 0);
}

// Round 20
// 4839.992 us; speedup vs baseline: 1.0477x; 1.0093x over previous
//
#include <hip/hip_runtime.h>
#include <hip/hip_bf16.h>

#define LL 1568
#define EE 384
#define DD 768
#define BB 4

typedef float f32x4 __attribute__((ext_vector_type(4)));
typedef float f32x2 __attribute__((ext_vector_type(2)));
typedef unsigned short u16x2 __attribute__((ext_vector_type(2)));
typedef unsigned short u16x4 __attribute__((ext_vector_type(4)));
typedef unsigned short u16x8 __attribute__((ext_vector_type(8)));
typedef __bf16 bf16x8 __attribute__((ext_vector_type(8)));

__device__ inline unsigned short f2bf(float f) {
    unsigned int u = __builtin_bit_cast(unsigned int, f);
    u += 0x7fffu + ((u >> 16) & 1u);
    return (unsigned short)(u >> 16);
}
__device__ inline float bf2f(unsigned short u) {
    unsigned int v = ((unsigned int)u) << 16;
    return __builtin_bit_cast(float, v);
}
__device__ inline float silu_f(float v) { return v / (1.f + __expf(-v)); }
__device__ inline float exp2_f(float v) { return __builtin_amdgcn_exp2f(v); }

// ---------------- weight fp32 -> bf16 ----------------
__global__ __launch_bounds__(256) void k_cvt(const float* __restrict__ src,
                                             unsigned short* __restrict__ dst, int n4) {
    int i = blockIdx.x * 256 + threadIdx.x;
    int stride = gridDim.x * 256;
    for (; i < n4; i += stride) {
        f32x4 v = *(const f32x4*)(src + (size_t)i * 4);
        u16x4 o;
#pragma unroll
        for (int j = 0; j < 4; j++) o[j] = f2bf(v[j]);
        *(u16x4*)(dst + (size_t)i * 4) = o;
    }
}

// xpw [24][56][768] f32 -> [24][64][768] bf16 (rows 56..63 zero)
__global__ __launch_bounds__(256) void k_pad_xpw(const float* __restrict__ src,
                                                 unsigned short* __restrict__ dst) {
    const int total = 24 * 64 * 768;
    for (int i = blockIdx.x * 256 + threadIdx.x; i < total; i += gridDim.x * 256) {
        int l = i / (64 * 768);
        int r = (i / 768) % 64;
        int dcol = i % 768;
        dst[i] = (r < 56) ? f2bf(src[((size_t)l * 56 + r) * 768 + dcol]) : (unsigned short)0;
    }
}

// dtw [24][768][24] f32 -> [24][768][32] bf16 (cols 24..31 zero)
__global__ __launch_bounds__(256) void k_pad_dtw(const float* __restrict__ src,
                                                 unsigned short* __restrict__ dst) {
    const int total = 24 * 768 * 32;
    for (int i = blockIdx.x * 256 + threadIdx.x; i < total; i += gridDim.x * 256) {
        int kk = i & 31;
        int nrow = i >> 5;
        dst[i] = (kk < 24) ? f2bf(src[(size_t)nrow * 24 + kk]) : (unsigned short)0;
    }
}

// ---------------- patch extraction (bf16 out) ----------------
__global__ __launch_bounds__(256) void k_patch(const float* __restrict__ x,
                                               unsigned short* __restrict__ patches) {
    int bid = blockIdx.x;
    int b = bid / LL, rr = bid % LL, t = rr / 196, pp = rr % 196, hp = pp / 14, wp = pp % 14;
    for (int k = threadIdx.x; k < 768; k += 256) {
        int c = k >> 8, rem = k & 255, i = rem >> 4, j = rem & 15;
        patches[(size_t)bid * 768 + k] =
            f2bf(x[(((size_t)(b * 3 + c) * 8 + t) * 224 + hp * 16 + i) * 224 + wp * 16 + j]);
    }
}

// ---------------- GEMM: C[m][n] = sum_k A[m][k] * W[n][k]  (bf16 in, MFMA) ----------------
// EPI: 0 none, 1 patch-add (bf16 Cb), 2 bias+relu (f32), 3 bias+softplus (bf16, dual-dir W)
// MTILE/NTILE: output tile (rows/cols); 4 waves arranged 2x2 over the tile
template <int EPI, bool ASUM, bool OUTBF, int MTILE = 128, int NTILE = 128>
__global__ __launch_bounds__(256) void k_gemm(
    const unsigned short* __restrict__ A, const unsigned short* __restrict__ A2,
    const unsigned short* __restrict__ W, const unsigned short* __restrict__ W2,
    float* __restrict__ C, unsigned short* __restrict__ Cb, int K, int ldc,
    const float* __restrict__ bias, const float* __restrict__ bias2,
    const float* __restrict__ pos, const float* __restrict__ tpos) {
    const int tid = threadIdx.x;
    const int m0 = blockIdx.y * MTILE;
    const int n0 = blockIdx.x * NTILE;
    constexpr int MFRAG = MTILE / 32;       // m-fragments per wave
    constexpr int NFRAG = NTILE / 32;       // n-fragments per wave
    constexpr int ALOAD = MTILE / 64;
    constexpr int WLOAD = NTILE / 64;
    __shared__ unsigned short As[MTILE * 40];
    __shared__ unsigned short Ws[NTILE * 40];
    const int sr = tid >> 2;
    const int skc = tid & 3;

    const unsigned short* Wp = W;
    const float* biasp = bias;
    if constexpr (EPI == 3) {
        if (m0 >= 6272) { Wp = W2; biasp = bias2; }
    }

    f32x4 acc[MFRAG][NFRAG];
#pragma unroll
    for (int mi = 0; mi < MFRAG; mi++)
#pragma unroll
        for (int ni = 0; ni < NFRAG; ni++) acc[mi][ni] = (f32x4){0.f, 0.f, 0.f, 0.f};

    const int lane = tid & 63;
    const int wv = tid >> 6;
    const int wm = (wv & 1) * (MTILE / 2);
    const int wn = (wv >> 1) * (NTILE / 2);
    const int lr = lane & 15;
    const int kg = lane >> 4;

    u16x8 ar[ALOAD], wr_[WLOAD];
    auto loadT = [&](int kt) {
#pragma unroll
        for (int i = 0; i < ALOAD; i++) {
            size_t ka = (size_t)(m0 + sr + 64 * i) * K + kt * 32 + skc * 8;
            u16x8 v = *(const u16x8*)(A + ka);
            if constexpr (ASUM) {
                u16x8 v2 = *(const u16x8*)(A2 + ka);
#pragma unroll
                for (int j = 0; j < 8; j++) v[j] = f2bf(bf2f(v[j]) + bf2f(v2[j]));
            }
            ar[i] = v;
        }
#pragma unroll
        for (int i = 0; i < WLOAD; i++)
            wr_[i] = *(const u16x8*)(Wp + (size_t)(n0 + sr + 64 * i) * K + kt * 32 + skc * 8);
    };

    const int nK = K >> 5;
    loadT(0);
    for (int kt = 0; kt < nK; ++kt) {
#pragma unroll
        for (int i = 0; i < ALOAD; i++)
            *(u16x8*)&As[(sr + 64 * i) * 40 + skc * 8] = ar[i];
#pragma unroll
        for (int i = 0; i < WLOAD; i++)
            *(u16x8*)&Ws[(sr + 64 * i) * 40 + skc * 8] = wr_[i];
        __syncthreads();
        if (kt + 1 < nK) loadT(kt + 1);
        bf16x8 af[MFRAG], bfm[NFRAG];
#pragma unroll
        for (int mi = 0; mi < MFRAG; mi++)
            af[mi] = *(const bf16x8*)&As[(wm + mi * 16 + lr) * 40 + kg * 8];
#pragma unroll
        for (int ni = 0; ni < NFRAG; ni++)
            bfm[ni] = *(const bf16x8*)&Ws[(wn + ni * 16 + lr) * 40 + kg * 8];
#pragma unroll
        for (int mi = 0; mi < MFRAG; mi++)
#pragma unroll
            for (int ni = 0; ni < NFRAG; ni++)
                acc[mi][ni] = __builtin_amdgcn_mfma_f32_16x16x32_bf16(af[mi], bfm[ni], acc[mi][ni], 0, 0, 0);
        __syncthreads();
    }

#pragma unroll
    for (int mi = 0; mi < MFRAG; mi++)
#pragma unroll
        for (int ni = 0; ni < NFRAG; ni++)
#pragma unroll
            for (int j = 0; j < 4; j++) {
                int m = m0 + wm + mi * 16 + kg * 4 + j;
                int n = n0 + wn + ni * 16 + lr;
                float v = acc[mi][ni][j];
                if constexpr (EPI == 1) {
                    int rr = m % LL;
                    int t = rr / 196, p = rr % 196;
                    v += bias[n] + pos[p * EE + n] + tpos[t * EE + n];
                    Cb[(size_t)m * ldc + n] = f2bf(v);
                } else if constexpr (EPI == 2) {
                    v += bias[n];
                    v = fmaxf(v, 0.f);
                    C[(size_t)m * ldc + n] = v;
                } else if constexpr (EPI == 3) {
                    v += biasp[n];
                    float sp = (v > 20.f) ? v : log1pf(__expf(v));
                    Cb[(size_t)m * ldc + n] = f2bf(sp);
                } else {
                    if constexpr (OUTBF)
                        Cb[(size_t)m * ldc + n] = f2bf(v);
                    else
                        C[(size_t)m * ldc + n] = v;
                }
            }
}

// ---------------- importance logits + sigmoid scale (bf16 hidden in-place) ----------------
__global__ __launch_bounds__(64) void k_logits(const float* __restrict__ h1, const float* __restrict__ w2,
                                               const float* __restrict__ b2,
                                               unsigned short* __restrict__ xseq,
                                               float* __restrict__ logits_out) {
    int row = blockIdx.x;
    int lane = threadIdx.x;
    float acc = 0.f;
#pragma unroll
    for (int i = 0; i < 6; i++) {
        int e = lane + i * 64;
        acc += h1[(size_t)row * EE + e] * w2[e];
    }
#pragma unroll
    for (int off = 32; off >= 1; off >>= 1) acc += __shfl_xor(acc, off);
    float logit = acc + b2[0];
    if (lane == 0) logits_out[row] = logit;
    float sg = 1.f / (1.f + __expf(-logit));
#pragma unroll
    for (int i = 0; i < 6; i++) {
        int e = lane + i * 64;
        size_t idx = (size_t)row * EE + e;
        xseq[idx] = f2bf(bf2f(xseq[idx]) * sg);
    }
}

// ---------------- residual add + rmsnorm (bf16 hidden, f32 resid) ----------------
template <bool OBF>
__global__ __launch_bounds__(256) void k_norm(const unsigned short* __restrict__ hidden,
                                              float* __restrict__ resid,
                                              const float* __restrict__ wn, float* __restrict__ outf,
                                              unsigned short* __restrict__ outb,
                                              int first, int writeResid) {
    int row = blockIdx.x * 4 + (threadIdx.x >> 6);
    int lane = threadIdx.x & 63;
    size_t base = (size_t)row * EE;
    float v[6];
    float ss = 0.f;
#pragma unroll
    for (int i = 0; i < 6; i++) {
        int e = lane + i * 64;
        float h = bf2f(hidden[base + e]);
        float r = first ? 0.f : resid[base + e];
        float s = h + r;
        v[i] = s;
        ss += s * s;
    }
#pragma unroll
    for (int off = 32; off >= 1; off >>= 1) ss += __shfl_xor(ss, off);
    if (writeResid) {
#pragma unroll
        for (int i = 0; i < 6; i++) resid[base + lane + i * 64] = v[i];
    }
    float sc = rsqrtf(ss * (1.f / 384.f) + 1e-5f);
#pragma unroll
    for (int i = 0; i < 6; i++) {
        int e = lane + i * 64;
        float o = v[i] * sc * wn[e];
        if constexpr (OBF)
            outb[base + e] = f2bf(o);
        else
            outf[base + e] = o;
    }
}

// ---------------- conv1d + silu -> xtb (bf16, [dir][b][t][d]) ----------------
__global__ __launch_bounds__(256) void k_conv(
    const unsigned short* __restrict__ xz,
    const float* __restrict__ cw_f, const float* __restrict__ cb_f,
    const float* __restrict__ cw_b, const float* __restrict__ cb_b,
    unsigned short* __restrict__ xtb) {
    const int tid = threadIdx.x;
    if (tid >= 192) return;
    const int b = blockIdx.y, dir = blockIdx.z;
    const float* cw = dir ? cw_b : cw_f;
    const float* cb = dir ? cb_b : cb_f;
    const int o = tid % 96, tg = tid / 96;
    const int t0 = blockIdx.x * 16 + tg * 8;
    const int d0 = o * 8;
    const size_t xzb = (size_t)b * LL * 1536;
    const size_t obase = ((size_t)dir * BB + b) * LL;

    f32x4 wq[8];
    float bv[8];
#pragma unroll
    for (int j = 0; j < 8; j++) {
        wq[j] = *(const f32x4*)&cw[(d0 + j) * 4];
        bv[j] = cb[d0 + j];
    }

    auto loadrow = [&](int t) -> u16x8 {
        if (t < 0) return (u16x8){0, 0, 0, 0, 0, 0, 0, 0};
        int phys = dir ? (LL - 1 - t) : t;
        return *(const u16x8*)&xz[xzb + (size_t)phys * 1536 + d0];
    };

    float f0[8], f1[8], f2[8];
    u16x8 v;
    v = loadrow(t0 - 3);
#pragma unroll
    for (int j = 0; j < 8; j++) f0[j] = bf2f(v[j]);
    v = loadrow(t0 - 2);
#pragma unroll
    for (int j = 0; j < 8; j++) f1[j] = bf2f(v[j]);
    v = loadrow(t0 - 1);
#pragma unroll
    for (int j = 0; j < 8; j++) f2[j] = bf2f(v[j]);

    for (int s = 0; s < 8; ++s) {
        int t = t0 + s;
        v = loadrow(t);
        float f3[8];
        u16x8 outv;
#pragma unroll
        for (int j = 0; j < 8; j++) {
            f3[j] = bf2f(v[j]);
            float cv = wq[j][0] * f0[j] + wq[j][1] * f1[j] + wq[j][2] * f2[j] + wq[j][3] * f3[j] + bv[j];
            outv[j] = f2bf(silu_f(cv));
        }
        *(u16x8*)&xtb[(obase + t) * 768 + d0] = outv;
#pragma unroll
        for (int j = 0; j < 8; j++) { f0[j] = f1[j]; f1[j] = f2[j]; f2[j] = f3[j]; }
    }
}

// ---------------- dbc GEMM: 32-row tiles, [12544 rows] x [64 cols] x K=768 -> dt_low / B / C ----------------
// grid 392 blocks; LDS 7.5 KB -> multi-block co-residency
__global__ __launch_bounds__(256) void k_dbc(
    const unsigned short* __restrict__ xtb,
    const unsigned short* __restrict__ xpwb_f, const unsigned short* __restrict__ xpwb_b,
    unsigned short* __restrict__ dtlow, float* __restrict__ Bm, float* __restrict__ Cm) {
    const int tid = threadIdx.x;
    const int m0 = blockIdx.x * 32;
    const unsigned short* W = (m0 >= 6272) ? xpwb_b : xpwb_f;
    __shared__ unsigned short As[32 * 40];
    __shared__ unsigned short Ws[64 * 40];
    const int sr = tid >> 2, skc = tid & 3;
    const int ar_row = tid >> 3, ar_oct = (tid >> 1) & 3;  // unused pattern guard
    const int lane = tid & 63, wv = tid >> 6;
    const int lr = lane & 15, kg = lane >> 4;

    f32x4 acc[2];
#pragma unroll
    for (int mi = 0; mi < 2; mi++) acc[mi] = (f32x4){0.f, 0.f, 0.f, 0.f};

    u16x8 ar, wr_;
    const bool doA = (tid < 128);
    const int arow = tid >> 2;          // 0..31 when tid<128
    auto loadT = [&](int kt) {
        if (doA)
            ar = *(const u16x8*)(xtb + (size_t)(m0 + arow) * 768 + kt * 32 + skc * 8);
        wr_ = *(const u16x8*)(W + (size_t)sr * 768 + kt * 32 + skc * 8);
    };
    loadT(0);
    for (int kt = 0; kt < 24; ++kt) {
        if (doA) *(u16x8*)&As[arow * 40 + skc * 8] = ar;
        *(u16x8*)&Ws[sr * 40 + skc * 8] = wr_;
        __syncthreads();
        if (kt + 1 < 24) loadT(kt + 1);
        bf16x8 bfm = *(const bf16x8*)&Ws[(wv * 16 + lr) * 40 + kg * 8];
#pragma unroll
        for (int mi = 0; mi < 2; mi++) {
            bf16x8 af = *(const bf16x8*)&As[(mi * 16 + lr) * 40 + kg * 8];
            acc[mi] = __builtin_amdgcn_mfma_f32_16x16x32_bf16(af, bfm, acc[mi], 0, 0, 0);
        }
        __syncthreads();
    }
#pragma unroll
    for (int mi = 0; mi < 2; mi++)
#pragma unroll
        for (int j = 0; j < 4; j++) {
            int row = m0 + mi * 16 + kg * 4 + j;
            int cc = wv * 16 + lr;
            float vv = acc[mi][j];
            if (cc < 24) dtlow[(size_t)row * 32 + cc] = f2bf(vv);
            else if (cc < 40) Bm[(size_t)row * 16 + (cc - 24)] = vv;
            else if (cc < 56) Cm[(size_t)row * 16 + (cc - 40)] = vv;
            else dtlow[(size_t)row * 32 + (cc - 32)] = 0;
        }
}

// ---------------- chunked 2-pass selective scan: 2 d's per thread (shared B/C), 32 chunks of 49 ----------------
// 512 threads = 16 dlane-pairs x 32 chunks; grid (24,4,2)
__global__ __launch_bounds__(512) void k_scan(
    const unsigned short* __restrict__ xtb, const unsigned short* __restrict__ dtb,
    const unsigned short* __restrict__ xz,
    const float* __restrict__ Bmat, const float* __restrict__ Cmat,
    const float* __restrict__ Alog_f, const float* __restrict__ Alog_b,
    const float* __restrict__ Dp_f, const float* __restrict__ Dp_b,
    unsigned short* __restrict__ ybuf) {
    const int tid = threadIdx.x;
    const int dl = tid & 15, c = tid >> 4;  // 16 lane-pairs, 32 chunks
    const int d0 = blockIdx.x * 32 + dl * 2;
    const int b = blockIdx.y, dir = blockIdx.z;
    const float* Alog = dir ? Alog_b : Alog_f;
    const float* Dp = dir ? Dp_b : Dp_f;
    const int t0 = c * 49;

    __shared__ float Ssh[32][32][17];   // [chunk][d-local][n] (+1 pad)
    __shared__ float sdt_sh[32][32];

    float anA[16], anB[16];
#pragma unroll
    for (int n = 0; n < 16; n++) {
        anA[n] = -__expf(Alog[d0 * 16 + n]) * 1.44269504f;
        anB[n] = -__expf(Alog[(d0 + 1) * 16 + n]) * 1.44269504f;
    }
    bool unif = (anA[0] != 0.f) && (anB[0] != 0.f);
#pragma unroll
    for (int n = 1; n < 16; n++) {
        float rA = anA[n] / anA[0];
        float rB = anB[n] / anB[0];
        unif = unif && (fabsf(rA - (float)(n + 1)) < 1e-3f) && (fabsf(rB - (float)(n + 1)) < 1e-3f);
    }
    const float a0A = anA[0], a0B = anB[0];
    float DdA = Dp[d0], DdB = Dp[d0 + 1];

    const size_t dbase = ((size_t)dir * BB + b) * LL;
    const size_t rowb = dbase * 768 + d0;

    f32x2 SA[8], SB[8];
#pragma unroll
    for (int k = 0; k < 8; k++) { SA[k] = (f32x2){0.f, 0.f}; SB[k] = (f32x2){0.f, 0.f}; }
    float sumA = 0.f, sumB = 0.f;

    // ---- pass 1 ----
    for (int s = 0; s < 49; ++s) {
        int t = t0 + s;
        unsigned int xv = *(const unsigned int*)&xtb[rowb + (size_t)t * 768];
        unsigned int dv = *(const unsigned int*)&dtb[rowb + (size_t)t * 768];
        float xtA = bf2f((unsigned short)xv), xtB = bf2f((unsigned short)(xv >> 16));
        float dtA = bf2f((unsigned short)dv), dtB = bf2f((unsigned short)(dv >> 16));
        sumA += dtA; sumB += dtB;
        float dxA = dtA * xtA, dxB = dtB * xtB;
        const f32x4* Bp = (const f32x4*)(Bmat + (dbase + t) * 16);
        f32x4 Bq[4] = {Bp[0], Bp[1], Bp[2], Bp[3]};
        const f32x2* B2 = (const f32x2*)Bq;
        f32x2 dxA2 = {dxA, dxA}, dxB2 = {dxB, dxB};
        if (unif) {
            float pA = exp2_f(dtA * a0A), pB = exp2_f(dtB * a0B);
            float qA = pA * pA, qB = pB * pB;
            f32x2 qA2 = {qA, qA}, qB2 = {qB, qB};
            f32x2 pwA[8], pwB[8];
            pwA[0] = (f32x2){pA, qA};
            pwB[0] = (f32x2){pB, qB};
#pragma unroll
            for (int j = 1; j < 8; j++) { pwA[j] = pwA[j - 1] * qA2; pwB[j] = pwB[j - 1] * qB2; }
#pragma unroll
            for (int k = 0; k < 8; k++) {
                SA[k] = SA[k] * pwA[k] + dxA2 * B2[k];
                SB[k] = SB[k] * pwB[k] + dxB2 * B2[k];
            }
        } else {
#pragma unroll
            for (int n = 0; n < 16; n++) {
                float bqv = ((const float*)Bq)[n];
                float eA = exp2_f(dtA * anA[n]);
                float eB = exp2_f(dtB * anB[n]);
                SA[n >> 1][n & 1] = SA[n >> 1][n & 1] * eA + dxA * bqv;
                SB[n >> 1][n & 1] = SB[n >> 1][n & 1] * eB + dxB * bqv;
            }
        }
    }
#pragma unroll
    for (int n = 0; n < 16; n++) {
        Ssh[c][dl * 2][n] = SA[n >> 1][n & 1];
        Ssh[c][dl * 2 + 1][n] = SB[n >> 1][n & 1];
    }
    sdt_sh[c][dl * 2] = sumA;
    sdt_sh[c][dl * 2 + 1] = sumB;
    __syncthreads();

    // ---- combine: exclusive prefix over 32 chunks; 512 threads -> (d-local, n2) pairs ----
    {
        int cdl = tid & 31, n2 = tid >> 5;  // d-local 0..31, n 0..15
        float a_n = -__expf(Alog[(blockIdx.x * 32 + cdl) * 16 + n2]) * 1.44269504f;
        float H = 0.f;
#pragma unroll
        for (int c2 = 0; c2 < 32; c2++) {
            float P = exp2_f(a_n * sdt_sh[c2][cdl]);
            float tmp = Ssh[c2][cdl][n2];
            Ssh[c2][cdl][n2] = H;
            H = H * P + tmp;
        }
    }
    __syncthreads();

    // ---- pass 2 ----
#pragma unroll
    for (int n = 0; n < 16; n++) {
        SA[n >> 1][n & 1] = Ssh[c][dl * 2][n];
        SB[n >> 1][n & 1] = Ssh[c][dl * 2 + 1][n];
    }
    for (int s = 0; s < 49; ++s) {
        int t = t0 + s;
        unsigned int xv = *(const unsigned int*)&xtb[rowb + (size_t)t * 768];
        unsigned int dv = *(const unsigned int*)&dtb[rowb + (size_t)t * 768];
        float xtA = bf2f((unsigned short)xv), xtB = bf2f((unsigned short)(xv >> 16));
        float dtA = bf2f((unsigned short)dv), dtB = bf2f((unsigned short)(dv >> 16));
        float dxA = dtA * xtA, dxB = dtB * xtB;
        const f32x4* Bp = (const f32x4*)(Bmat + (dbase + t) * 16);
        f32x4 Bq[4] = {Bp[0], Bp[1], Bp[2], Bp[3]};
        const f32x4* Cp = (const f32x4*)(Cmat + (dbase + t) * 16);
        f32x4 Cq[4] = {Cp[0], Cp[1], Cp[2], Cp[3]};
        const f32x2* B2 = (const f32x2*)Bq;
        const f32x2* C2 = (const f32x2*)Cq;
        f32x2 dxA2 = {dxA, dxA}, dxB2 = {dxB, dxB};
        f32x2 yA2 = {0.f, 0.f}, yB2 = {0.f, 0.f};
        if (unif) {
            float pA = exp2_f(dtA * a0A), pB = exp2_f(dtB * a0B);
            float qA = pA * pA, qB = pB * pB;
            f32x2 qA2 = {qA, qA}, qB2 = {qB, qB};
            f32x2 pwA[8], pwB[8];
            pwA[0] = (f32x2){pA, qA};
            pwB[0] = (f32x2){pB, qB};
#pragma unroll
            for (int j = 1; j < 8; j++) { pwA[j] = pwA[j - 1] * qA2; pwB[j] = pwB[j - 1] * qB2; }
#pragma unroll
            for (int k = 0; k < 8; k++) {
                SA[k] = SA[k] * pwA[k] + dxA2 * B2[k];
                SB[k] = SB[k] * pwB[k] + dxB2 * B2[k];
                yA2 = yA2 + SA[k] * C2[k];
                yB2 = yB2 + SB[k] * C2[k];
            }
        } else {
#pragma unroll
            for (int n = 0; n < 16; n++) {
                float bqv = ((const float*)Bq)[n];
                float cqv = ((const float*)Cq)[n];
                float eA = exp2_f(dtA * anA[n]);
                float eB = exp2_f(dtB * anB[n]);
                float sA = SA[n >> 1][n & 1] * eA + dxA * bqv;
                float sB = SB[n >> 1][n & 1] * eB + dxB * bqv;
                SA[n >> 1][n & 1] = sA;
                SB[n >> 1][n & 1] = sB;
                yA2[n & 1] += sA * cqv;
                yB2[n & 1] += sB * cqv;
            }
        }
        float yA = yA2[0] + yA2[1] + xtA * DdA;
        float yB = yB2[0] + yB2[1] + xtB * DdB;
        int pt = dir ? (LL - 1 - t) : t;
        unsigned int zv2 = *(const unsigned int*)&xz[((size_t)b * LL + pt) * 1536 + 768 + d0];
        float zA = bf2f((unsigned short)zv2), zB = bf2f((unsigned short)(zv2 >> 16));
        unsigned int yo = (unsigned int)f2bf(yA * silu_f(zA)) |
                          ((unsigned int)f2bf(yB * silu_f(zB)) << 16);
        *(unsigned int*)&ybuf[rowb + (size_t)pt * 768] = yo;
    }
}

// ---------------- launcher ----------------
extern "C" void kernel_launch(void* const* d_in, const int* in_sizes, int n_in,
                              void* d_out, int out_size, void* d_ws, size_t ws_size,
                              hipStream_t stream) {
    const float* x        = (const float*)d_in[0];
    const float* patch_w  = (const float*)d_in[1];
    const float* patch_b  = (const float*)d_in[2];
    const float* pos_emb  = (const float*)d_in[3];
    const float* tpos     = (const float*)d_in[4];
    const float* imp_w1   = (const float*)d_in[5];
    const float* imp_b1   = (const float*)d_in[6];
    const float* imp_w2   = (const float*)d_in[7];
    const float* imp_b2   = (const float*)d_in[8];
    const float* in_w     = (const float*)d_in[9];
    const float* out_w    = (const float*)d_in[10];
    const float* norm_w   = (const float*)d_in[11];
    const float* norm_f_w = (const float*)d_in[12];
    const float* conv_w   = (const float*)d_in[13];
    const float* conv_b   = (const float*)d_in[14];
    const float* xp_w     = (const float*)d_in[15];
    const float* dt_w     = (const float*)d_in[16];
    const float* dt_b     = (const float*)d_in[17];
    const float* A_log    = (const float*)d_in[18];
    const float* Dp       = (const float*)d_in[19];
    const float* conv_w_b = (const float*)d_in[20];
    const float* conv_b_b = (const float*)d_in[21];
    const float* xp_w_b   = (const float*)d_in[22];
    const float* dt_w_b   = (const float*)d_in[23];
    const float* dt_b_b   = (const float*)d_in[24];
    const float* A_log_b  = (const float*)d_in[25];
    const float* D_b      = (const float*)d_in[26];

    float* out = (float*)d_out;
    float* logits_out = out + 2408448;

    char* wsb = (char*)d_ws;
    size_t off = 0;
    auto carve = [&](size_t bytes) { char* p = wsb + off; off += bytes; return p; };

    unsigned short* in_wb    = (unsigned short*)carve(28311552);  // 24*1536*384
    unsigned short* out_wb   = (unsigned short*)carve(14155776);  // 24*384*768
    unsigned short* patch_wb = (unsigned short*)carve(589824);
    unsigned short* imp_w1b  = (unsigned short*)carve(294912);
    unsigned short* xpwb_f   = (unsigned short*)carve(2359296);   // 24*64*768
    unsigned short* xpwb_b   = (unsigned short*)carve(2359296);
    unsigned short* dtwb_f   = (unsigned short*)carve(1179648);   // 24*768*32
    unsigned short* dtwb_b   = (unsigned short*)carve(1179648);
    unsigned short* hidden   = (unsigned short*)carve(4816896);   // 6272*384 bf16
    float*          resid    = (float*)carve(9633792);
    unsigned short* hn       = (unsigned short*)carve(4816896);
    unsigned short* xzb      = (unsigned short*)carve(19267584);  // 4*1568*1536 bf16
    unsigned short* xtb      = (unsigned short*)carve(19267584);  // 2*4*1568*768 bf16
    unsigned short* g_dt     = (unsigned short*)carve(19267584);
    unsigned short* dtlow    = (unsigned short*)carve(802816);    // 12544*32 bf16
    float*          Bm       = (float*)carve(802816);             // 12544*16 f32
    float*          Cm       = (float*)carve(802816);
    unsigned short* ybuf     = (unsigned short*)carve(19267584);

    float*          h1       = (float*)xtb;            // pre-loop only
    unsigned short* patches  = (unsigned short*)ybuf;  // pre-loop only

    // weight prep
    k_cvt<<<2048, 256, 0, stream>>>(in_w, in_wb, 3538944);
    k_cvt<<<2048, 256, 0, stream>>>(out_w, out_wb, 1769472);
    k_cvt<<<288, 256, 0, stream>>>(patch_w, patch_wb, 73728);
    k_cvt<<<144, 256, 0, stream>>>(imp_w1, imp_w1b, 36864);
    k_pad_xpw<<<1024, 256, 0, stream>>>(xp_w, xpwb_f);
    k_pad_xpw<<<1024, 256, 0, stream>>>(xp_w_b, xpwb_b);
    k_pad_dtw<<<1024, 256, 0, stream>>>(dt_w, dtwb_f);
    k_pad_dtw<<<1024, 256, 0, stream>>>(dt_w_b, dtwb_b);

    k_patch<<<6272, 256, 0, stream>>>(x, patches);
    k_gemm<1, false, true><<<dim3(3, 49), 256, 0, stream>>>(patches, nullptr, patch_wb, nullptr,
                                                            nullptr, hidden, 768, 384,
                                                            patch_b, nullptr, pos_emb, tpos);
    k_gemm<2, false, false><<<dim3(3, 49), 256, 0, stream>>>(hidden, nullptr, imp_w1b, nullptr,
                                                             h1, nullptr, 384, 384,
                                                             imp_b1, nullptr, nullptr, nullptr);
    k_logits<<<6272, 64, 0, stream>>>(h1, imp_w2, imp_b2, hidden, logits_out);

    for (int l = 0; l < 24; ++l) {
        k_norm<true><<<1568, 256, 0, stream>>>(hidden, resid, norm_w + l * 384, nullptr, hn,
                                               (l == 0) ? 1 : 0, 1);
        k_gemm<0, false, true><<<dim3(12, 49), 256, 0, stream>>>(hn, nullptr, in_wb + (size_t)l * 589824,
                                                                 nullptr, nullptr, xzb, 384, 1536,
                                                                 nullptr, nullptr, nullptr, nullptr);
        k_conv<<<dim3(98, 4, 2), 256, 0, stream>>>(xzb, conv_w + l * 3072, conv_b + l * 768,
                                                   conv_w_b + l * 3072, conv_b_b + l * 768, xtb);
        k_dbc<<<392, 256, 0, stream>>>(xtb, xpwb_f + (size_t)l * 49152, xpwb_b + (size_t)l * 49152,
                                       dtlow, Bm, Cm);
        k_gemm<3, false, true><<<dim3(6, 98), 256, 0, stream>>>(dtlow, nullptr,
                                                                dtwb_f + (size_t)l * 24576,
                                                                dtwb_b + (size_t)l * 24576,
                                                                nullptr, g_dt, 32, 768,
                                                                dt_b + l * 768, dt_b_b + l * 768,
                                                                nullptr, nullptr);
        k_scan<<<dim3(24, 4, 2), 512, 0, stream>>>(
            xtb, g_dt, xzb, Bm, Cm,
            A_log + l * 12288, A_log_b + l * 12288,
            Dp + l * 768, D_b + l * 768,
            ybuf);
        // out-proj: M-split tiles (64x128) -> 294 blocks
        k_gemm<0, true, true, 64, 128><<<dim3(3, 98), 256, 0, stream>>>(ybuf, ybuf + 4816896,
                                                                        out_wb + (size_t)l * 294912, nullptr,
                                                                        nullptr, hidden, 768, 384,
                                                                        nullptr, nullptr, nullptr, nullptr);
    }
    k_norm<false><<<1568, 256, 0, stream>>>(hidden, resid, norm_f_w, out, nullptr, 0, 0);
}

// Round 21
// 4492.262 us; speedup vs baseline: 1.1288x; 1.0774x over previous
//
#include <hip/hip_runtime.h>
#include <hip/hip_bf16.h>

#define LL 1568
#define EE 384
#define DD 768
#define BB 4

typedef float f32x4 __attribute__((ext_vector_type(4)));
typedef float f32x2 __attribute__((ext_vector_type(2)));
typedef unsigned short u16x2 __attribute__((ext_vector_type(2)));
typedef unsigned short u16x4 __attribute__((ext_vector_type(4)));
typedef unsigned short u16x8 __attribute__((ext_vector_type(8)));
typedef __bf16 bf16x8 __attribute__((ext_vector_type(8)));

__device__ inline unsigned short f2bf(float f) {
    unsigned int u = __builtin_bit_cast(unsigned int, f);
    u += 0x7fffu + ((u >> 16) & 1u);
    return (unsigned short)(u >> 16);
}
__device__ inline float bf2f(unsigned short u) {
    unsigned int v = ((unsigned int)u) << 16;
    return __builtin_bit_cast(float, v);
}
__device__ inline float silu_f(float v) { return v / (1.f + __expf(-v)); }
__device__ inline float exp2_f(float v) { return __builtin_amdgcn_exp2f(v); }

// ---------------- weight fp32 -> bf16 ----------------
__global__ __launch_bounds__(256) void k_cvt(const float* __restrict__ src,
                                             unsigned short* __restrict__ dst, int n4) {
    int i = blockIdx.x * 256 + threadIdx.x;
    int stride = gridDim.x * 256;
    for (; i < n4; i += stride) {
        f32x4 v = *(const f32x4*)(src + (size_t)i * 4);
        u16x4 o;
#pragma unroll
        for (int j = 0; j < 4; j++) o[j] = f2bf(v[j]);
        *(u16x4*)(dst + (size_t)i * 4) = o;
    }
}

// xpw [24][56][768] f32 -> [24][64][768] bf16 (rows 56..63 zero)
__global__ __launch_bounds__(256) void k_pad_xpw(const float* __restrict__ src,
                                                 unsigned short* __restrict__ dst) {
    const int total = 24 * 64 * 768;
    for (int i = blockIdx.x * 256 + threadIdx.x; i < total; i += gridDim.x * 256) {
        int l = i / (64 * 768);
        int r = (i / 768) % 64;
        int dcol = i % 768;
        dst[i] = (r < 56) ? f2bf(src[((size_t)l * 56 + r) * 768 + dcol]) : (unsigned short)0;
    }
}

// dtw [24][768][24] f32 -> [24][768][32] bf16 (cols 24..31 zero)
__global__ __launch_bounds__(256) void k_pad_dtw(const float* __restrict__ src,
                                                 unsigned short* __restrict__ dst) {
    const int total = 24 * 768 * 32;
    for (int i = blockIdx.x * 256 + threadIdx.x; i < total; i += gridDim.x * 256) {
        int kk = i & 31;
        int nrow = i >> 5;
        dst[i] = (kk < 24) ? f2bf(src[(size_t)nrow * 24 + kk]) : (unsigned short)0;
    }
}

// ---------------- patch extraction (bf16 out) ----------------
__global__ __launch_bounds__(256) void k_patch(const float* __restrict__ x,
                                               unsigned short* __restrict__ patches) {
    int bid = blockIdx.x;
    int b = bid / LL, rr = bid % LL, t = rr / 196, pp = rr % 196, hp = pp / 14, wp = pp % 14;
    for (int k = threadIdx.x; k < 768; k += 256) {
        int c = k >> 8, rem = k & 255, i = rem >> 4, j = rem & 15;
        patches[(size_t)bid * 768 + k] =
            f2bf(x[(((size_t)(b * 3 + c) * 8 + t) * 224 + hp * 16 + i) * 224 + wp * 16 + j]);
    }
}

// ---------------- GEMM: C[m][n] = sum_k A[m][k] * W[n][k]  (bf16 in, MFMA) ----------------
// EPI: 0 none, 1 patch-add (bf16 Cb), 2 bias+relu (f32), 3 bias+softplus (bf16, dual-dir W)
// MTILE/NTILE: output tile (rows/cols); 4 waves arranged 2x2 over the tile
template <int EPI, bool ASUM, bool OUTBF, int MTILE = 128, int NTILE = 128>
__global__ __launch_bounds__(256) void k_gemm(
    const unsigned short* __restrict__ A, const unsigned short* __restrict__ A2,
    const unsigned short* __restrict__ W, const unsigned short* __restrict__ W2,
    float* __restrict__ C, unsigned short* __restrict__ Cb, int K, int ldc,
    const float* __restrict__ bias, const float* __restrict__ bias2,
    const float* __restrict__ pos, const float* __restrict__ tpos) {
    const int tid = threadIdx.x;
    const int m0 = blockIdx.y * MTILE;
    const int n0 = blockIdx.x * NTILE;
    constexpr int MFRAG = MTILE / 32;       // m-fragments per wave
    constexpr int NFRAG = NTILE / 32;       // n-fragments per wave
    constexpr int ALOAD = MTILE / 64;
    constexpr int WLOAD = NTILE / 64;
    __shared__ unsigned short As[MTILE * 40];
    __shared__ unsigned short Ws[NTILE * 40];
    const int sr = tid >> 2;
    const int skc = tid & 3;

    const unsigned short* Wp = W;
    const float* biasp = bias;
    if constexpr (EPI == 3) {
        if (m0 >= 6272) { Wp = W2; biasp = bias2; }
    }

    f32x4 acc[MFRAG][NFRAG];
#pragma unroll
    for (int mi = 0; mi < MFRAG; mi++)
#pragma unroll
        for (int ni = 0; ni < NFRAG; ni++) acc[mi][ni] = (f32x4){0.f, 0.f, 0.f, 0.f};

    const int lane = tid & 63;
    const int wv = tid >> 6;
    const int wm = (wv & 1) * (MTILE / 2);
    const int wn = (wv >> 1) * (NTILE / 2);
    const int lr = lane & 15;
    const int kg = lane >> 4;

    u16x8 ar[ALOAD], wr_[WLOAD];
    auto loadT = [&](int kt) {
#pragma unroll
        for (int i = 0; i < ALOAD; i++) {
            size_t ka = (size_t)(m0 + sr + 64 * i) * K + kt * 32 + skc * 8;
            u16x8 v = *(const u16x8*)(A + ka);
            if constexpr (ASUM) {
                u16x8 v2 = *(const u16x8*)(A2 + ka);
#pragma unroll
                for (int j = 0; j < 8; j++) v[j] = f2bf(bf2f(v[j]) + bf2f(v2[j]));
            }
            ar[i] = v;
        }
#pragma unroll
        for (int i = 0; i < WLOAD; i++)
            wr_[i] = *(const u16x8*)(Wp + (size_t)(n0 + sr + 64 * i) * K + kt * 32 + skc * 8);
    };

    const int nK = K >> 5;
    loadT(0);
    for (int kt = 0; kt < nK; ++kt) {
#pragma unroll
        for (int i = 0; i < ALOAD; i++)
            *(u16x8*)&As[(sr + 64 * i) * 40 + skc * 8] = ar[i];
#pragma unroll
        for (int i = 0; i < WLOAD; i++)
            *(u16x8*)&Ws[(sr + 64 * i) * 40 + skc * 8] = wr_[i];
        __syncthreads();
        if (kt + 1 < nK) loadT(kt + 1);
        bf16x8 af[MFRAG], bfm[NFRAG];
#pragma unroll
        for (int mi = 0; mi < MFRAG; mi++)
            af[mi] = *(const bf16x8*)&As[(wm + mi * 16 + lr) * 40 + kg * 8];
#pragma unroll
        for (int ni = 0; ni < NFRAG; ni++)
            bfm[ni] = *(const bf16x8*)&Ws[(wn + ni * 16 + lr) * 40 + kg * 8];
#pragma unroll
        for (int mi = 0; mi < MFRAG; mi++)
#pragma unroll
            for (int ni = 0; ni < NFRAG; ni++)
                acc[mi][ni] = __builtin_amdgcn_mfma_f32_16x16x32_bf16(af[mi], bfm[ni], acc[mi][ni], 0, 0, 0);
        __syncthreads();
    }

#pragma unroll
    for (int mi = 0; mi < MFRAG; mi++)
#pragma unroll
        for (int ni = 0; ni < NFRAG; ni++)
#pragma unroll
            for (int j = 0; j < 4; j++) {
                int m = m0 + wm + mi * 16 + kg * 4 + j;
                int n = n0 + wn + ni * 16 + lr;
                float v = acc[mi][ni][j];
                if constexpr (EPI == 1) {
                    int rr = m % LL;
                    int t = rr / 196, p = rr % 196;
                    v += bias[n] + pos[p * EE + n] + tpos[t * EE + n];
                    Cb[(size_t)m * ldc + n] = f2bf(v);
                } else if constexpr (EPI == 2) {
                    v += bias[n];
                    v = fmaxf(v, 0.f);
                    C[(size_t)m * ldc + n] = v;
                } else if constexpr (EPI == 3) {
                    v += biasp[n];
                    float sp = (v > 20.f) ? v : log1pf(__expf(v));
                    Cb[(size_t)m * ldc + n] = f2bf(sp);
                } else {
                    if constexpr (OUTBF)
                        Cb[(size_t)m * ldc + n] = f2bf(v);
                    else
                        C[(size_t)m * ldc + n] = v;
                }
            }
}

// ---------------- importance logits + sigmoid scale (bf16 hidden in-place) ----------------
__global__ __launch_bounds__(64) void k_logits(const float* __restrict__ h1, const float* __restrict__ w2,
                                               const float* __restrict__ b2,
                                               unsigned short* __restrict__ xseq,
                                               float* __restrict__ logits_out) {
    int row = blockIdx.x;
    int lane = threadIdx.x;
    float acc = 0.f;
#pragma unroll
    for (int i = 0; i < 6; i++) {
        int e = lane + i * 64;
        acc += h1[(size_t)row * EE + e] * w2[e];
    }
#pragma unroll
    for (int off = 32; off >= 1; off >>= 1) acc += __shfl_xor(acc, off);
    float logit = acc + b2[0];
    if (lane == 0) logits_out[row] = logit;
    float sg = 1.f / (1.f + __expf(-logit));
#pragma unroll
    for (int i = 0; i < 6; i++) {
        int e = lane + i * 64;
        size_t idx = (size_t)row * EE + e;
        xseq[idx] = f2bf(bf2f(xseq[idx]) * sg);
    }
}

// ---------------- residual add + rmsnorm (bf16 hidden, f32 resid) ----------------
template <bool OBF>
__global__ __launch_bounds__(256) void k_norm(const unsigned short* __restrict__ hidden,
                                              float* __restrict__ resid,
                                              const float* __restrict__ wn, float* __restrict__ outf,
                                              unsigned short* __restrict__ outb,
                                              int first, int writeResid) {
    int row = blockIdx.x * 4 + (threadIdx.x >> 6);
    int lane = threadIdx.x & 63;
    size_t base = (size_t)row * EE;
    float v[6];
    float ss = 0.f;
#pragma unroll
    for (int i = 0; i < 6; i++) {
        int e = lane + i * 64;
        float h = bf2f(hidden[base + e]);
        float r = first ? 0.f : resid[base + e];
        float s = h + r;
        v[i] = s;
        ss += s * s;
    }
#pragma unroll
    for (int off = 32; off >= 1; off >>= 1) ss += __shfl_xor(ss, off);
    if (writeResid) {
#pragma unroll
        for (int i = 0; i < 6; i++) resid[base + lane + i * 64] = v[i];
    }
    float sc = rsqrtf(ss * (1.f / 384.f) + 1e-5f);
#pragma unroll
    for (int i = 0; i < 6; i++) {
        int e = lane + i * 64;
        float o = v[i] * sc * wn[e];
        if constexpr (OBF)
            outb[base + e] = f2bf(o);
        else
            outf[base + e] = o;
    }
}

// ---------------- conv1d + silu -> xtb (bf16, [dir][b][t][d]) ----------------
__global__ __launch_bounds__(256) void k_conv(
    const unsigned short* __restrict__ xz,
    const float* __restrict__ cw_f, const float* __restrict__ cb_f,
    const float* __restrict__ cw_b, const float* __restrict__ cb_b,
    unsigned short* __restrict__ xtb) {
    const int tid = threadIdx.x;
    if (tid >= 192) return;
    const int b = blockIdx.y, dir = blockIdx.z;
    const float* cw = dir ? cw_b : cw_f;
    const float* cb = dir ? cb_b : cb_f;
    const int o = tid % 96, tg = tid / 96;
    const int t0 = blockIdx.x * 16 + tg * 8;
    const int d0 = o * 8;
    const size_t xzb = (size_t)b * LL * 1536;
    const size_t obase = ((size_t)dir * BB + b) * LL;

    f32x4 wq[8];
    float bv[8];
#pragma unroll
    for (int j = 0; j < 8; j++) {
        wq[j] = *(const f32x4*)&cw[(d0 + j) * 4];
        bv[j] = cb[d0 + j];
    }

    auto loadrow = [&](int t) -> u16x8 {
        if (t < 0) return (u16x8){0, 0, 0, 0, 0, 0, 0, 0};
        int phys = dir ? (LL - 1 - t) : t;
        return *(const u16x8*)&xz[xzb + (size_t)phys * 1536 + d0];
    };

    float f0[8], f1[8], f2[8];
    u16x8 v;
    v = loadrow(t0 - 3);
#pragma unroll
    for (int j = 0; j < 8; j++) f0[j] = bf2f(v[j]);
    v = loadrow(t0 - 2);
#pragma unroll
    for (int j = 0; j < 8; j++) f1[j] = bf2f(v[j]);
    v = loadrow(t0 - 1);
#pragma unroll
    for (int j = 0; j < 8; j++) f2[j] = bf2f(v[j]);

    for (int s = 0; s < 8; ++s) {
        int t = t0 + s;
        v = loadrow(t);
        float f3[8];
        u16x8 outv;
#pragma unroll
        for (int j = 0; j < 8; j++) {
            f3[j] = bf2f(v[j]);
            float cv = wq[j][0] * f0[j] + wq[j][1] * f1[j] + wq[j][2] * f2[j] + wq[j][3] * f3[j] + bv[j];
            outv[j] = f2bf(silu_f(cv));
        }
        *(u16x8*)&xtb[(obase + t) * 768 + d0] = outv;
#pragma unroll
        for (int j = 0; j < 8; j++) { f0[j] = f1[j]; f1[j] = f2[j]; f2[j] = f3[j]; }
    }
}

// ---------------- dbc GEMM: 32-row tiles, [12544 rows] x [64 cols] x K=768 -> dt_low / B / C ----------------
// grid 392 blocks; LDS 7.5 KB -> multi-block co-residency
__global__ __launch_bounds__(256) void k_dbc(
    const unsigned short* __restrict__ xtb,
    const unsigned short* __restrict__ xpwb_f, const unsigned short* __restrict__ xpwb_b,
    unsigned short* __restrict__ dtlow, float* __restrict__ Bm, float* __restrict__ Cm) {
    const int tid = threadIdx.x;
    const int m0 = blockIdx.x * 32;
    const unsigned short* W = (m0 >= 6272) ? xpwb_b : xpwb_f;
    __shared__ unsigned short As[32 * 40];
    __shared__ unsigned short Ws[64 * 40];
    const int sr = tid >> 2, skc = tid & 3;
    const int lane = tid & 63, wv = tid >> 6;
    const int lr = lane & 15, kg = lane >> 4;

    f32x4 acc[2];
#pragma unroll
    for (int mi = 0; mi < 2; mi++) acc[mi] = (f32x4){0.f, 0.f, 0.f, 0.f};

    u16x8 ar, wr_;
    const bool doA = (tid < 128);
    const int arow = tid >> 2;          // 0..31 when tid<128
    auto loadT = [&](int kt) {
        if (doA)
            ar = *(const u16x8*)(xtb + (size_t)(m0 + arow) * 768 + kt * 32 + skc * 8);
        wr_ = *(const u16x8*)(W + (size_t)sr * 768 + kt * 32 + skc * 8);
    };
    loadT(0);
    for (int kt = 0; kt < 24; ++kt) {
        if (doA) *(u16x8*)&As[arow * 40 + skc * 8] = ar;
        *(u16x8*)&Ws[sr * 40 + skc * 8] = wr_;
        __syncthreads();
        if (kt + 1 < 24) loadT(kt + 1);
        bf16x8 bfm = *(const bf16x8*)&Ws[(wv * 16 + lr) * 40 + kg * 8];
#pragma unroll
        for (int mi = 0; mi < 2; mi++) {
            bf16x8 af = *(const bf16x8*)&As[(mi * 16 + lr) * 40 + kg * 8];
            acc[mi] = __builtin_amdgcn_mfma_f32_16x16x32_bf16(af, bfm, acc[mi], 0, 0, 0);
        }
        __syncthreads();
    }
#pragma unroll
    for (int mi = 0; mi < 2; mi++)
#pragma unroll
        for (int j = 0; j < 4; j++) {
            int row = m0 + mi * 16 + kg * 4 + j;
            int cc = wv * 16 + lr;
            float vv = acc[mi][j];
            if (cc < 24) dtlow[(size_t)row * 32 + cc] = f2bf(vv);
            else if (cc < 40) Bm[(size_t)row * 16 + (cc - 24)] = vv;
            else if (cc < 56) Cm[(size_t)row * 16 + (cc - 40)] = vv;
            else dtlow[(size_t)row * 32 + (cc - 32)] = 0;
        }
}

// ---------------- chunked 2-pass selective scan: 2 d's per thread, software-pipelined loads ----------------
// 512 threads = 16 dlane-pairs x 32 chunks; grid (24,4,2)
__global__ __launch_bounds__(512) void k_scan(
    const unsigned short* __restrict__ xtb, const unsigned short* __restrict__ dtb,
    const unsigned short* __restrict__ xz,
    const float* __restrict__ Bmat, const float* __restrict__ Cmat,
    const float* __restrict__ Alog_f, const float* __restrict__ Alog_b,
    const float* __restrict__ Dp_f, const float* __restrict__ Dp_b,
    unsigned short* __restrict__ ybuf) {
    const int tid = threadIdx.x;
    const int dl = tid & 15, c = tid >> 4;  // 16 lane-pairs, 32 chunks
    const int d0 = blockIdx.x * 32 + dl * 2;
    const int b = blockIdx.y, dir = blockIdx.z;
    const float* Alog = dir ? Alog_b : Alog_f;
    const float* Dp = dir ? Dp_b : Dp_f;
    const int t0 = c * 49;

    __shared__ float Ssh[32][32][17];   // [chunk][d-local][n] (+1 pad)
    __shared__ float sdt_sh[32][32];

    float anA[16], anB[16];
#pragma unroll
    for (int n = 0; n < 16; n++) {
        anA[n] = -__expf(Alog[d0 * 16 + n]) * 1.44269504f;
        anB[n] = -__expf(Alog[(d0 + 1) * 16 + n]) * 1.44269504f;
    }
    bool unif = (anA[0] != 0.f) && (anB[0] != 0.f);
#pragma unroll
    for (int n = 1; n < 16; n++) {
        float rA = anA[n] / anA[0];
        float rB = anB[n] / anB[0];
        unif = unif && (fabsf(rA - (float)(n + 1)) < 1e-3f) && (fabsf(rB - (float)(n + 1)) < 1e-3f);
    }
    const float a0A = anA[0], a0B = anB[0];
    float DdA = Dp[d0], DdB = Dp[d0 + 1];

    const size_t dbase = ((size_t)dir * BB + b) * LL;
    const size_t rowb = dbase * 768 + d0;

    f32x2 SA[8], SB[8];
#pragma unroll
    for (int k = 0; k < 8; k++) { SA[k] = (f32x2){0.f, 0.f}; SB[k] = (f32x2){0.f, 0.f}; }
    float sumA = 0.f, sumB = 0.f;

    // ---- pass 1 (software-pipelined: loads for s+1 issued before compute of s) ----
    unsigned int xv = *(const unsigned int*)&xtb[rowb + (size_t)t0 * 768];
    unsigned int dv = *(const unsigned int*)&dtb[rowb + (size_t)t0 * 768];
    f32x4 Bq0 = ((const f32x4*)(Bmat + (dbase + t0) * 16))[0];
    f32x4 Bq1 = ((const f32x4*)(Bmat + (dbase + t0) * 16))[1];
    f32x4 Bq2 = ((const f32x4*)(Bmat + (dbase + t0) * 16))[2];
    f32x4 Bq3 = ((const f32x4*)(Bmat + (dbase + t0) * 16))[3];
    for (int s = 0; s < 49; ++s) {
        // prefetch next step
        unsigned int nxv = 0, ndv = 0;
        f32x4 nB0, nB1, nB2, nB3;
        if (s + 1 < 49) {
            int tn = t0 + s + 1;
            nxv = *(const unsigned int*)&xtb[rowb + (size_t)tn * 768];
            ndv = *(const unsigned int*)&dtb[rowb + (size_t)tn * 768];
            const f32x4* Bp = (const f32x4*)(Bmat + (dbase + tn) * 16);
            nB0 = Bp[0]; nB1 = Bp[1]; nB2 = Bp[2]; nB3 = Bp[3];
        }
        float xtA = bf2f((unsigned short)xv), xtB = bf2f((unsigned short)(xv >> 16));
        float dtA = bf2f((unsigned short)dv), dtB = bf2f((unsigned short)(dv >> 16));
        sumA += dtA; sumB += dtB;
        float dxA = dtA * xtA, dxB = dtB * xtB;
        f32x4 Bq[4] = {Bq0, Bq1, Bq2, Bq3};
        const f32x2* B2 = (const f32x2*)Bq;
        f32x2 dxA2 = {dxA, dxA}, dxB2 = {dxB, dxB};
        if (unif) {
            float pA = exp2_f(dtA * a0A), pB = exp2_f(dtB * a0B);
            float qA = pA * pA, qB = pB * pB;
            f32x2 qA2 = {qA, qA}, qB2 = {qB, qB};
            f32x2 pwA[8], pwB[8];
            pwA[0] = (f32x2){pA, qA};
            pwB[0] = (f32x2){pB, qB};
#pragma unroll
            for (int j = 1; j < 8; j++) { pwA[j] = pwA[j - 1] * qA2; pwB[j] = pwB[j - 1] * qB2; }
#pragma unroll
            for (int k = 0; k < 8; k++) {
                SA[k] = SA[k] * pwA[k] + dxA2 * B2[k];
                SB[k] = SB[k] * pwB[k] + dxB2 * B2[k];
            }
        } else {
#pragma unroll
            for (int n = 0; n < 16; n++) {
                float bqv = ((const float*)Bq)[n];
                float eA = exp2_f(dtA * anA[n]);
                float eB = exp2_f(dtB * anB[n]);
                SA[n >> 1][n & 1] = SA[n >> 1][n & 1] * eA + dxA * bqv;
                SB[n >> 1][n & 1] = SB[n >> 1][n & 1] * eB + dxB * bqv;
            }
        }
        xv = nxv; dv = ndv;
        Bq0 = nB0; Bq1 = nB1; Bq2 = nB2; Bq3 = nB3;
    }
#pragma unroll
    for (int n = 0; n < 16; n++) {
        Ssh[c][dl * 2][n] = SA[n >> 1][n & 1];
        Ssh[c][dl * 2 + 1][n] = SB[n >> 1][n & 1];
    }
    sdt_sh[c][dl * 2] = sumA;
    sdt_sh[c][dl * 2 + 1] = sumB;
    __syncthreads();

    // ---- combine: exclusive prefix over 32 chunks; 512 threads -> (d-local, n2) pairs ----
    {
        int cdl = tid & 31, n2 = tid >> 5;  // d-local 0..31, n 0..15
        float a_n = -__expf(Alog[(blockIdx.x * 32 + cdl) * 16 + n2]) * 1.44269504f;
        float H = 0.f;
#pragma unroll
        for (int c2 = 0; c2 < 32; c2++) {
            float P = exp2_f(a_n * sdt_sh[c2][cdl]);
            float tmp = Ssh[c2][cdl][n2];
            Ssh[c2][cdl][n2] = H;
            H = H * P + tmp;
        }
    }
    __syncthreads();

    // ---- pass 2 (software-pipelined) ----
#pragma unroll
    for (int n = 0; n < 16; n++) {
        SA[n >> 1][n & 1] = Ssh[c][dl * 2][n];
        SB[n >> 1][n & 1] = Ssh[c][dl * 2 + 1][n];
    }
    {
        int pt0 = dir ? (LL - 1 - t0) : t0;
        xv = *(const unsigned int*)&xtb[rowb + (size_t)t0 * 768];
        dv = *(const unsigned int*)&dtb[rowb + (size_t)t0 * 768];
        const f32x4* Bp = (const f32x4*)(Bmat + (dbase + t0) * 16);
        Bq0 = Bp[0]; Bq1 = Bp[1]; Bq2 = Bp[2]; Bq3 = Bp[3];
        f32x4 Cq0, Cq1, Cq2, Cq3;
        const f32x4* Cp = (const f32x4*)(Cmat + (dbase + t0) * 16);
        Cq0 = Cp[0]; Cq1 = Cp[1]; Cq2 = Cp[2]; Cq3 = Cp[3];
        unsigned int zv = *(const unsigned int*)&xz[((size_t)b * LL + pt0) * 1536 + 768 + d0];
        for (int s = 0; s < 49; ++s) {
            unsigned int nxv = 0, ndv = 0, nzv = 0;
            f32x4 nB0, nB1, nB2, nB3, nC0, nC1, nC2, nC3;
            if (s + 1 < 49) {
                int tn = t0 + s + 1;
                int ptn = dir ? (LL - 1 - tn) : tn;
                nxv = *(const unsigned int*)&xtb[rowb + (size_t)tn * 768];
                ndv = *(const unsigned int*)&dtb[rowb + (size_t)tn * 768];
                const f32x4* nBp = (const f32x4*)(Bmat + (dbase + tn) * 16);
                nB0 = nBp[0]; nB1 = nBp[1]; nB2 = nBp[2]; nB3 = nBp[3];
                const f32x4* nCp = (const f32x4*)(Cmat + (dbase + tn) * 16);
                nC0 = nCp[0]; nC1 = nCp[1]; nC2 = nCp[2]; nC3 = nCp[3];
                nzv = *(const unsigned int*)&xz[((size_t)b * LL + ptn) * 1536 + 768 + d0];
            }
            float xtA = bf2f((unsigned short)xv), xtB = bf2f((unsigned short)(xv >> 16));
            float dtA = bf2f((unsigned short)dv), dtB = bf2f((unsigned short)(dv >> 16));
            float dxA = dtA * xtA, dxB = dtB * xtB;
            f32x4 Bq[4] = {Bq0, Bq1, Bq2, Bq3};
            f32x4 Cq[4] = {Cq0, Cq1, Cq2, Cq3};
            const f32x2* B2 = (const f32x2*)Bq;
            const f32x2* C2 = (const f32x2*)Cq;
            f32x2 dxA2 = {dxA, dxA}, dxB2 = {dxB, dxB};
            f32x2 yA2 = {0.f, 0.f}, yB2 = {0.f, 0.f};
            if (unif) {
                float pA = exp2_f(dtA * a0A), pB = exp2_f(dtB * a0B);
                float qA = pA * pA, qB = pB * pB;
                f32x2 qA2 = {qA, qA}, qB2 = {qB, qB};
                f32x2 pwA[8], pwB[8];
                pwA[0] = (f32x2){pA, qA};
                pwB[0] = (f32x2){pB, qB};
#pragma unroll
                for (int j = 1; j < 8; j++) { pwA[j] = pwA[j - 1] * qA2; pwB[j] = pwB[j - 1] * qB2; }
#pragma unroll
                for (int k = 0; k < 8; k++) {
                    SA[k] = SA[k] * pwA[k] + dxA2 * B2[k];
                    SB[k] = SB[k] * pwB[k] + dxB2 * B2[k];
                    yA2 = yA2 + SA[k] * C2[k];
                    yB2 = yB2 + SB[k] * C2[k];
                }
            } else {
#pragma unroll
                for (int n = 0; n < 16; n++) {
                    float bqv = ((const float*)Bq)[n];
                    float cqv = ((const float*)Cq)[n];
                    float eA = exp2_f(dtA * anA[n]);
                    float eB = exp2_f(dtB * anB[n]);
                    float sA = SA[n >> 1][n & 1] * eA + dxA * bqv;
                    float sB = SB[n >> 1][n & 1] * eB + dxB * bqv;
                    SA[n >> 1][n & 1] = sA;
                    SB[n >> 1][n & 1] = sB;
                    yA2[n & 1] += sA * cqv;
                    yB2[n & 1] += sB * cqv;
                }
            }
            float yA = yA2[0] + yA2[1] + xtA * DdA;
            float yB = yB2[0] + yB2[1] + xtB * DdB;
            int pt = dir ? (LL - 1 - (t0 + s)) : (t0 + s);
            float zA = bf2f((unsigned short)zv), zB = bf2f((unsigned short)(zv >> 16));
            unsigned int yo = (unsigned int)f2bf(yA * silu_f(zA)) |
                              ((unsigned int)f2bf(yB * silu_f(zB)) << 16);
            *(unsigned int*)&ybuf[rowb + (size_t)pt * 768] = yo;
            xv = nxv; dv = ndv; zv = nzv;
            Bq0 = nB0; Bq1 = nB1; Bq2 = nB2; Bq3 = nB3;
            Cq0 = nC0; Cq1 = nC1; Cq2 = nC2; Cq3 = nC3;
        }
    }
}

// ---------------- launcher ----------------
extern "C" void kernel_launch(void* const* d_in, const int* in_sizes, int n_in,
                              void* d_out, int out_size, void* d_ws, size_t ws_size,
                              hipStream_t stream) {
    const float* x        = (const float*)d_in[0];
    const float* patch_w  = (const float*)d_in[1];
    const float* patch_b  = (const float*)d_in[2];
    const float* pos_emb  = (const float*)d_in[3];
    const float* tpos     = (const float*)d_in[4];
    const float* imp_w1   = (const float*)d_in[5];
    const float* imp_b1   = (const float*)d_in[6];
    const float* imp_w2   = (const float*)d_in[7];
    const float* imp_b2   = (const float*)d_in[8];
    const float* in_w     = (const float*)d_in[9];
    const float* out_w    = (const float*)d_in[10];
    const float* norm_w   = (const float*)d_in[11];
    const float* norm_f_w = (const float*)d_in[12];
    const float* conv_w   = (const float*)d_in[13];
    const float* conv_b   = (const float*)d_in[14];
    const float* xp_w     = (const float*)d_in[15];
    const float* dt_w     = (const float*)d_in[16];
    const float* dt_b     = (const float*)d_in[17];
    const float* A_log    = (const float*)d_in[18];
    const float* Dp       = (const float*)d_in[19];
    const float* conv_w_b = (const float*)d_in[20];
    const float* conv_b_b = (const float*)d_in[21];
    const float* xp_w_b   = (const float*)d_in[22];
    const float* dt_w_b   = (const float*)d_in[23];
    const float* dt_b_b   = (const float*)d_in[24];
    const float* A_log_b  = (const float*)d_in[25];
    const float* D_b      = (const float*)d_in[26];

    float* out = (float*)d_out;
    float* logits_out = out + 2408448;

    char* wsb = (char*)d_ws;
    size_t off = 0;
    auto carve = [&](size_t bytes) { char* p = wsb + off; off += bytes; return p; };

    unsigned short* in_wb    = (unsigned short*)carve(28311552);  // 24*1536*384
    unsigned short* out_wb   = (unsigned short*)carve(14155776);  // 24*384*768
    unsigned short* patch_wb = (unsigned short*)carve(589824);
    unsigned short* imp_w1b  = (unsigned short*)carve(294912);
    unsigned short* xpwb_f   = (unsigned short*)carve(2359296);   // 24*64*768
    unsigned short* xpwb_b   = (unsigned short*)carve(2359296);
    unsigned short* dtwb_f   = (unsigned short*)carve(1179648);   // 24*768*32
    unsigned short* dtwb_b   = (unsigned short*)carve(1179648);
    unsigned short* hidden   = (unsigned short*)carve(4816896);   // 6272*384 bf16
    float*          resid    = (float*)carve(9633792);
    unsigned short* hn       = (unsigned short*)carve(4816896);
    unsigned short* xzb      = (unsigned short*)carve(19267584);  // 4*1568*1536 bf16
    unsigned short* xtb      = (unsigned short*)carve(19267584);  // 2*4*1568*768 bf16
    unsigned short* g_dt     = (unsigned short*)carve(19267584);
    unsigned short* dtlow    = (unsigned short*)carve(802816);    // 12544*32 bf16
    float*          Bm       = (float*)carve(802816);             // 12544*16 f32
    float*          Cm       = (float*)carve(802816);
    unsigned short* ybuf     = (unsigned short*)carve(19267584);

    float*          h1       = (float*)xtb;            // pre-loop only
    unsigned short* patches  = (unsigned short*)ybuf;  // pre-loop only

    // weight prep
    k_cvt<<<2048, 256, 0, stream>>>(in_w, in_wb, 3538944);
    k_cvt<<<2048, 256, 0, stream>>>(out_w, out_wb, 1769472);
    k_cvt<<<288, 256, 0, stream>>>(patch_w, patch_wb, 73728);
    k_cvt<<<144, 256, 0, stream>>>(imp_w1, imp_w1b, 36864);
    k_pad_xpw<<<1024, 256, 0, stream>>>(xp_w, xpwb_f);
    k_pad_xpw<<<1024, 256, 0, stream>>>(xp_w_b, xpwb_b);
    k_pad_dtw<<<1024, 256, 0, stream>>>(dt_w, dtwb_f);
    k_pad_dtw<<<1024, 256, 0, stream>>>(dt_w_b, dtwb_b);

    k_patch<<<6272, 256, 0, stream>>>(x, patches);
    k_gemm<1, false, true><<<dim3(3, 49), 256, 0, stream>>>(patches, nullptr, patch_wb, nullptr,
                                                            nullptr, hidden, 768, 384,
                                                            patch_b, nullptr, pos_emb, tpos);
    k_gemm<2, false, false><<<dim3(3, 49), 256, 0, stream>>>(hidden, nullptr, imp_w1b, nullptr,
                                                             h1, nullptr, 384, 384,
                                                             imp_b1, nullptr, nullptr, nullptr);
    k_logits<<<6272, 64, 0, stream>>>(h1, imp_w2, imp_b2, hidden, logits_out);

    for (int l = 0; l < 24; ++l) {
        k_norm<true><<<1568, 256, 0, stream>>>(hidden, resid, norm_w + l * 384, nullptr, hn,
                                               (l == 0) ? 1 : 0, 1);
        k_gemm<0, false, true><<<dim3(12, 49), 256, 0, stream>>>(hn, nullptr, in_wb + (size_t)l * 589824,
                                                                 nullptr, nullptr, xzb, 384, 1536,
                                                                 nullptr, nullptr, nullptr, nullptr);
        k_conv<<<dim3(98, 4, 2), 256, 0, stream>>>(xzb, conv_w + l * 3072, conv_b + l * 768,
                                                   conv_w_b + l * 3072, conv_b_b + l * 768, xtb);
        k_dbc<<<392, 256, 0, stream>>>(xtb, xpwb_f + (size_t)l * 49152, xpwb_b + (size_t)l * 49152,
                                       dtlow, Bm, Cm);
        k_gemm<3, false, true><<<dim3(6, 98), 256, 0, stream>>>(dtlow, nullptr,
                                                                dtwb_f + (size_t)l * 24576,
                                                                dtwb_b + (size_t)l * 24576,
                                                                nullptr, g_dt, 32, 768,
                                                                dt_b + l * 768, dt_b_b + l * 768,
                                                                nullptr, nullptr);
        k_scan<<<dim3(24, 4, 2), 512, 0, stream>>>(
            xtb, g_dt, xzb, Bm, Cm,
            A_log + l * 12288, A_log_b + l * 12288,
            Dp + l * 768, D_b + l * 768,
            ybuf);
        // out-proj: M-split tiles (64x128) -> 294 blocks
        k_gemm<0, true, true, 64, 128><<<dim3(3, 98), 256, 0, stream>>>(ybuf, ybuf + 4816896,
                                                                        out_wb + (size_t)l * 294912, nullptr,
                                                                        nullptr, hidden, 768, 384,
                                                                        nullptr, nullptr, nullptr, nullptr);
    }
    k_norm<false><<<1568, 256, 0, stream>>>(hidden, resid, norm_f_w, out, nullptr, 0, 0);
}